// Round 1
// baseline (3268.996 us; speedup 1.0000x reference)
//
#include <hip/hip_runtime.h>
#include <math.h>

#define TV 32000
#define TD 512
#define TS 2048
#define TH 8
#define TF 2048
#define TL 4
#define TB 2
#define THD 64
#define TEPS 1e-5f
#define NBS (TB * TS)               // 4096 token rows
#define ND ((long)NBS * TD)         // 2097152 elements per activation buffer

// ---------------- embedding + sinusoidal positional encoding ----------------
__global__ __launch_bounds__(64) void embed_kernel(const int* __restrict__ tokens,
                                                   const float* __restrict__ emb,
                                                   float* __restrict__ x) {
    const int bs = blockIdx.x;              // 0 .. B*S-1
    const int s = bs & (TS - 1);            // S = 2048 (pow2)
    const int tok = tokens[bs];
    const float* e = emb + (long)tok * TD;
    float* xo = x + (long)bs * TD;
    const int d0 = threadIdx.x * 8;
#pragma unroll
    for (int j = 0; j < 8; ++j) {
        const int d = d0 + j;
        const float div = expf((float)(d & ~1) * (-9.210340371976184f / (float)TD));
        const float ang = (float)s * div;
        const float pe = (d & 1) ? cosf(ang) : sinf(ang);
        xo[d] = e[d] + pe;
    }
}

// ---------------- tiled fp32 GEMM: C[M,N] = A[M,K] @ W[K,N] (+bias, relu) ---
// block 256 threads (16x16), 64x64 tile, BK=16, each thread 4x4 outputs.
template <bool BIAS, bool RELU>
__global__ __launch_bounds__(256) void gemm_kernel(const float* __restrict__ A,
                                                   const float* __restrict__ W,
                                                   const float* __restrict__ bias,
                                                   float* __restrict__ C,
                                                   int M, int N, int K) {
    __shared__ float As[16][64];   // [k][m] (transposed A tile)
    __shared__ float Bs[16][64];   // [k][n]
    const int tid = threadIdx.x;
    const int tx = tid & 15, ty = tid >> 4;
    const int row0 = blockIdx.y * 64, col0 = blockIdx.x * 64;
    const int am = tid >> 2, akq = (tid & 3) * 4;   // A loader: row am, k-chunk akq
    const int bk = tid >> 4, bn = (tid & 15) * 4;   // B loader: k row bk, col bn
    float acc[4][4] = {};
    for (int k0 = 0; k0 < K; k0 += 16) {
        const float4 av = *(const float4*)(A + (long)(row0 + am) * K + k0 + akq);
        const float4 bv = *(const float4*)(W + (long)(k0 + bk) * N + col0 + bn);
        As[akq + 0][am] = av.x;
        As[akq + 1][am] = av.y;
        As[akq + 2][am] = av.z;
        As[akq + 3][am] = av.w;
        *(float4*)&Bs[bk][bn] = bv;
        __syncthreads();
#pragma unroll
        for (int kk = 0; kk < 16; ++kk) {
            const float4 a = *(const float4*)&As[kk][ty * 4];
            const float4 b = *(const float4*)&Bs[kk][tx * 4];
            acc[0][0] += a.x * b.x; acc[0][1] += a.x * b.y; acc[0][2] += a.x * b.z; acc[0][3] += a.x * b.w;
            acc[1][0] += a.y * b.x; acc[1][1] += a.y * b.y; acc[1][2] += a.y * b.z; acc[1][3] += a.y * b.w;
            acc[2][0] += a.z * b.x; acc[2][1] += a.z * b.y; acc[2][2] += a.z * b.z; acc[2][3] += a.z * b.w;
            acc[3][0] += a.w * b.x; acc[3][1] += a.w * b.y; acc[3][2] += a.w * b.z; acc[3][3] += a.w * b.w;
        }
        __syncthreads();
    }
    const int c = col0 + tx * 4;
#pragma unroll
    for (int i = 0; i < 4; ++i) {
        float4 o;
        o.x = acc[i][0]; o.y = acc[i][1]; o.z = acc[i][2]; o.w = acc[i][3];
        if (BIAS) { o.x += bias[c]; o.y += bias[c + 1]; o.z += bias[c + 2]; o.w += bias[c + 3]; }
        if (RELU) {
            o.x = fmaxf(o.x, 0.f); o.y = fmaxf(o.y, 0.f);
            o.z = fmaxf(o.z, 0.f); o.w = fmaxf(o.w, 0.f);
        }
        *(float4*)(C + (long)(row0 + ty * 4 + i) * N + c) = o;
    }
}

// ---------------- fused flash attention (fp32), one block per (b,h,q-tile) --
// q/k/v are [B,S,D] with head h at columns h*64..h*64+63.
__global__ __launch_bounds__(256) void attn_kernel(const float* __restrict__ qg,
                                                   const float* __restrict__ kg,
                                                   const float* __restrict__ vg,
                                                   float* __restrict__ og) {
    __shared__ float Qs[64][64];   // [d][r], pre-scaled by 1/8
    __shared__ float Ks[64][64];   // [d][c]
    __shared__ float Ps[64][64];   // [kk][r]  (P transposed)
    __shared__ float Vs[64][64];   // [kk][d]
    const int qt = blockIdx.x, h = blockIdx.y, b = blockIdx.z;
    const long hbase = ((long)b * TS) * TD + h * THD;
    const int tid = threadIdx.x;
    const int tx = tid & 15, ty = tid >> 4;
    const int lr = tid >> 2;             // row this thread loads (0..63)
    const int ld0 = (tid & 3) * 16;      // d-chunk base

    {   // load Q tile transposed + scaled
        const float* src = qg + hbase + (long)(qt * 64 + lr) * TD + ld0;
#pragma unroll
        for (int jj = 0; jj < 4; ++jj) {
            const float4 t4 = *(const float4*)(src + jj * 4);
            const int d = ld0 + jj * 4;
            Qs[d + 0][lr] = t4.x * 0.125f;
            Qs[d + 1][lr] = t4.y * 0.125f;
            Qs[d + 2][lr] = t4.z * 0.125f;
            Qs[d + 3][lr] = t4.w * 0.125f;
        }
    }

    float m_run[4], l_run[4], Oacc[4][4] = {};
#pragma unroll
    for (int i = 0; i < 4; ++i) { m_run[i] = -1e30f; l_run[i] = 0.f; }

    for (int kt = 0; kt < TS / 64; ++kt) {
        __syncthreads();   // previous iteration's LDS reads complete (and Q ready, iter 0)
        {   // load K (transposed) and V tiles
            const float* ksrc = kg + hbase + (long)(kt * 64 + lr) * TD + ld0;
            const float* vsrc = vg + hbase + (long)(kt * 64 + lr) * TD + ld0;
#pragma unroll
            for (int jj = 0; jj < 4; ++jj) {
                const float4 t4 = *(const float4*)(ksrc + jj * 4);
                const int d = ld0 + jj * 4;
                Ks[d + 0][lr] = t4.x; Ks[d + 1][lr] = t4.y;
                Ks[d + 2][lr] = t4.z; Ks[d + 3][lr] = t4.w;
                *(float4*)&Vs[lr][d] = *(const float4*)(vsrc + jj * 4);
            }
        }
        __syncthreads();

        // scores S = (Q*0.125) @ K^T : thread owns rows ty*4+i, cols tx*4+j
        float sacc[4][4] = {};
#pragma unroll 16
        for (int d = 0; d < 64; ++d) {
            const float4 a = *(const float4*)&Qs[d][ty * 4];
            const float4 bq = *(const float4*)&Ks[d][tx * 4];
            sacc[0][0] += a.x * bq.x; sacc[0][1] += a.x * bq.y; sacc[0][2] += a.x * bq.z; sacc[0][3] += a.x * bq.w;
            sacc[1][0] += a.y * bq.x; sacc[1][1] += a.y * bq.y; sacc[1][2] += a.y * bq.z; sacc[1][3] += a.y * bq.w;
            sacc[2][0] += a.z * bq.x; sacc[2][1] += a.z * bq.y; sacc[2][2] += a.z * bq.z; sacc[2][3] += a.z * bq.w;
            sacc[3][0] += a.w * bq.x; sacc[3][1] += a.w * bq.y; sacc[3][2] += a.w * bq.z; sacc[3][3] += a.w * bq.w;
        }

        // online softmax (row-wise across the 16 tx lanes)
#pragma unroll
        for (int i = 0; i < 4; ++i) {
            float rm = fmaxf(fmaxf(sacc[i][0], sacc[i][1]), fmaxf(sacc[i][2], sacc[i][3]));
            rm = fmaxf(rm, __shfl_xor(rm, 1, 64));
            rm = fmaxf(rm, __shfl_xor(rm, 2, 64));
            rm = fmaxf(rm, __shfl_xor(rm, 4, 64));
            rm = fmaxf(rm, __shfl_xor(rm, 8, 64));
            const float mnew = fmaxf(m_run[i], rm);
            float rs = 0.f;
#pragma unroll
            for (int j = 0; j < 4; ++j) { sacc[i][j] = __expf(sacc[i][j] - mnew); rs += sacc[i][j]; }
            rs += __shfl_xor(rs, 1, 64);
            rs += __shfl_xor(rs, 2, 64);
            rs += __shfl_xor(rs, 4, 64);
            rs += __shfl_xor(rs, 8, 64);
            const float scl = __expf(m_run[i] - mnew);
            l_run[i] = l_run[i] * scl + rs;
            m_run[i] = mnew;
#pragma unroll
            for (int j = 0; j < 4; ++j) Oacc[i][j] *= scl;
        }

        // write P transposed for the PV matmul
#pragma unroll
        for (int i = 0; i < 4; ++i)
#pragma unroll
            for (int j = 0; j < 4; ++j) Ps[tx * 4 + j][ty * 4 + i] = sacc[i][j];
        __syncthreads();

        // O += P @ V
#pragma unroll 16
        for (int kk = 0; kk < 64; ++kk) {
            const float4 a = *(const float4*)&Ps[kk][ty * 4];
            const float4 bv = *(const float4*)&Vs[kk][tx * 4];
            Oacc[0][0] += a.x * bv.x; Oacc[0][1] += a.x * bv.y; Oacc[0][2] += a.x * bv.z; Oacc[0][3] += a.x * bv.w;
            Oacc[1][0] += a.y * bv.x; Oacc[1][1] += a.y * bv.y; Oacc[1][2] += a.y * bv.z; Oacc[1][3] += a.y * bv.w;
            Oacc[2][0] += a.z * bv.x; Oacc[2][1] += a.z * bv.y; Oacc[2][2] += a.z * bv.z; Oacc[2][3] += a.z * bv.w;
            Oacc[3][0] += a.w * bv.x; Oacc[3][1] += a.w * bv.y; Oacc[3][2] += a.w * bv.z; Oacc[3][3] += a.w * bv.w;
        }
    }

#pragma unroll
    for (int i = 0; i < 4; ++i) {
        const float inv = 1.f / l_run[i];
        float4 o;
        o.x = Oacc[i][0] * inv; o.y = Oacc[i][1] * inv;
        o.z = Oacc[i][2] * inv; o.w = Oacc[i][3] * inv;
        *(float4*)(og + hbase + (long)(qt * 64 + ty * 4 + i) * TD + tx * 4) = o;
    }
}

// ---------------- fused residual-add + LayerNorm ----------------------------
__global__ __launch_bounds__(64) void addln_kernel(const float* __restrict__ a,
                                                   const float* __restrict__ res,
                                                   const float* __restrict__ g,
                                                   const float* __restrict__ bt,
                                                   float* __restrict__ out) {
    const int row = blockIdx.x;
    const int d0 = threadIdx.x * 8;
    const float* pa = a + (long)row * TD + d0;
    const float* pr = res + (long)row * TD + d0;
    float v[8];
    const float4 a0 = *(const float4*)pa, a1 = *(const float4*)(pa + 4);
    const float4 r0 = *(const float4*)pr, r1 = *(const float4*)(pr + 4);
    v[0] = a0.x + r0.x; v[1] = a0.y + r0.y; v[2] = a0.z + r0.z; v[3] = a0.w + r0.w;
    v[4] = a1.x + r1.x; v[5] = a1.y + r1.y; v[6] = a1.z + r1.z; v[7] = a1.w + r1.w;
    float s = 0.f, s2 = 0.f;
#pragma unroll
    for (int j = 0; j < 8; ++j) { s += v[j]; s2 += v[j] * v[j]; }
#pragma unroll
    for (int m = 1; m < 64; m <<= 1) {
        s += __shfl_xor(s, m, 64);
        s2 += __shfl_xor(s2, m, 64);
    }
    const float mean = s * (1.f / TD);
    const float var = s2 * (1.f / TD) - mean * mean;
    const float rstd = rsqrtf(var + TEPS);
    const float* pg = g + d0;
    const float* pb = bt + d0;
    float* po = out + (long)row * TD + d0;
    float4 o0, o1;
    o0.x = (v[0] - mean) * rstd * pg[0] + pb[0];
    o0.y = (v[1] - mean) * rstd * pg[1] + pb[1];
    o0.z = (v[2] - mean) * rstd * pg[2] + pb[2];
    o0.w = (v[3] - mean) * rstd * pg[3] + pb[3];
    o1.x = (v[4] - mean) * rstd * pg[4] + pb[4];
    o1.y = (v[5] - mean) * rstd * pg[5] + pb[5];
    o1.z = (v[6] - mean) * rstd * pg[6] + pb[6];
    o1.w = (v[7] - mean) * rstd * pg[7] + pb[7];
    *(float4*)po = o0;
    *(float4*)(po + 4) = o1;
}

extern "C" void kernel_launch(void* const* d_in, const int* in_sizes, int n_in,
                              void* d_out, int out_size, void* d_ws, size_t ws_size,
                              hipStream_t stream) {
    const int* tokens = (const int*)d_in[0];
    const float* emb = (const float*)d_in[1];
    const float* wq = (const float*)d_in[2];
    const float* wk = (const float*)d_in[3];
    const float* wv = (const float*)d_in[4];
    const float* wo = (const float*)d_in[5];
    const float* w1 = (const float*)d_in[6];
    const float* b1 = (const float*)d_in[7];
    const float* w2 = (const float*)d_in[8];
    const float* b2 = (const float*)d_in[9];
    const float* g1 = (const float*)d_in[10];
    const float* be1 = (const float*)d_in[11];
    const float* g2 = (const float*)d_in[12];
    const float* be2 = (const float*)d_in[13];

    float* ws = (float*)d_ws;
    float* x = ws;                // [B*S, D]
    float* qb = ws + ND;
    float* kb = ws + 2 * ND;
    float* vb = ws + 3 * ND;
    float* ao = ws + 4 * ND;
    float* tmp = ws + 5 * ND;
    float* ff = qb;               // reuse q/k/v/ao region: B*S*F = 4*ND floats
    float* out = (float*)d_out;

    embed_kernel<<<NBS, 64, 0, stream>>>(tokens, emb, x);

    const dim3 gD(TD / 64, NBS / 64);   // (8, 64)
    const dim3 gF(TF / 64, NBS / 64);   // (32, 64)
    const dim3 gA(TS / 64, TH, TB);     // (32, 8, 2)

    for (int l = 0; l < TL; ++l) {
        const float* Wq = wq + (long)l * TD * TD;
        const float* Wk = wk + (long)l * TD * TD;
        const float* Wv = wv + (long)l * TD * TD;
        const float* Wo = wo + (long)l * TD * TD;
        const float* W1 = w1 + (long)l * TD * TF;
        const float* B1 = b1 + (long)l * TF;
        const float* W2 = w2 + (long)l * TF * TD;
        const float* B2 = b2 + (long)l * TD;

        gemm_kernel<false, false><<<gD, 256, 0, stream>>>(x, Wq, nullptr, qb, NBS, TD, TD);
        gemm_kernel<false, false><<<gD, 256, 0, stream>>>(x, Wk, nullptr, kb, NBS, TD, TD);
        gemm_kernel<false, false><<<gD, 256, 0, stream>>>(x, Wv, nullptr, vb, NBS, TD, TD);
        attn_kernel<<<gA, 256, 0, stream>>>(qb, kb, vb, ao);
        gemm_kernel<false, false><<<gD, 256, 0, stream>>>(ao, Wo, nullptr, tmp, NBS, TD, TD);
        addln_kernel<<<NBS, 64, 0, stream>>>(tmp, x, g1 + (long)l * TD, be1 + (long)l * TD, x);
        gemm_kernel<true, true><<<gF, 256, 0, stream>>>(x, W1, B1, ff, NBS, TF, TD);
        gemm_kernel<true, false><<<gD, 256, 0, stream>>>(ff, W2, B2, tmp, NBS, TD, TF);
        float* dst = (l == TL - 1) ? out : x;
        addln_kernel<<<NBS, 64, 0, stream>>>(tmp, x, g2 + (long)l * TD, be2 + (long)l * TD, dst);
    }
}

// Round 2
// 1194.631 us; speedup vs baseline: 2.7364x; 2.7364x over previous
//
#include <hip/hip_runtime.h>
#include <math.h>

#define TV 32000
#define TD 512
#define TS 2048
#define TH 8
#define TF 2048
#define TL 4
#define TB 2
#define THD 64
#define TEPS 1e-5f
#define NBS (TB * TS)               // 4096 token rows
#define ND ((long)NBS * TD)         // 2097152 elements per activation buffer

typedef short bf16x8 __attribute__((ext_vector_type(8)));
typedef float f32x4 __attribute__((ext_vector_type(4)));
typedef __attribute__((address_space(3))) void lds_void;
typedef const __attribute__((address_space(1))) void gl_void;

__device__ __forceinline__ unsigned short f2bf(float f) {
    unsigned u = __builtin_bit_cast(unsigned, f);
    unsigned r = (u + 0x7fffu + ((u >> 16) & 1u)) >> 16;
    return (unsigned short)r;
}

__device__ __forceinline__ f32x4 zf4() {
    f32x4 z = {0.f, 0.f, 0.f, 0.f};
    return z;
}

// ---------------- embedding + sinusoidal positional encoding ----------------
__global__ __launch_bounds__(64) void embed_kernel(const int* __restrict__ tokens,
                                                   const float* __restrict__ emb,
                                                   float* __restrict__ x,
                                                   short* __restrict__ xb) {
    const int bs = blockIdx.x;
    const int s = bs & (TS - 1);
    const int tok = tokens[bs];
    const float* e = emb + (long)tok * TD;
    const int d0 = threadIdx.x * 8;
    float v[8];
#pragma unroll
    for (int j = 0; j < 8; ++j) {
        const int d = d0 + j;
        const float div = expf((float)(d & ~1) * (-9.210340371976184f / (float)TD));
        const float ang = (float)s * div;
        const float pe = (d & 1) ? cosf(ang) : sinf(ang);
        v[j] = e[d] + pe;
    }
    float* xo = x + (long)bs * TD + d0;
    float4 o0, o1;
    o0.x = v[0]; o0.y = v[1]; o0.z = v[2]; o0.w = v[3];
    o1.x = v[4]; o1.y = v[5]; o1.z = v[6]; o1.w = v[7];
    *(float4*)xo = o0;
    *(float4*)(xo + 4) = o1;
    bf16x8 t;
#pragma unroll
    for (int j = 0; j < 8; ++j) t[j] = (short)f2bf(v[j]);
    *(bf16x8*)(xb + (long)bs * TD + d0) = t;
}

// ---------------- weight prep: fp32 [K,N] -> bf16 [N,K], all 6 mats/layer ---
__global__ __launch_bounds__(256) void wprep_kernel(const float* __restrict__ wq,
                                                    const float* __restrict__ wk,
                                                    const float* __restrict__ wv,
                                                    const float* __restrict__ wo,
                                                    const float* __restrict__ w1,
                                                    const float* __restrict__ w2,
                                                    int l,
                                                    short* __restrict__ qkvT,
                                                    short* __restrict__ woT,
                                                    short* __restrict__ w1T,
                                                    short* __restrict__ w2T) {
    __shared__ float tile[32][33];
    const int t = blockIdx.x;
    const float* src;
    short* dst;
    int K, N, kt, nt;
    if (t < 1024) {
        const int mat = t >> 8, tt = t & 255;
        kt = tt >> 4; nt = tt & 15; K = 512; N = 512;
        const float* s4 = (mat == 0) ? wq : (mat == 1) ? wk : (mat == 2) ? wv : wo;
        src = s4 + (long)l * 512 * 512;
        dst = (mat < 3) ? qkvT + mat * 512 * 512 : woT;
    } else if (t < 2048) {
        const int tt = t - 1024;
        kt = tt & 15; nt = tt >> 4; K = 512; N = 2048;
        src = w1 + (long)l * 512 * 2048; dst = w1T;
    } else {
        const int tt = t - 2048;
        kt = tt >> 4; nt = tt & 15; K = 2048; N = 512;
        src = w2 + (long)l * 2048 * 512; dst = w2T;
    }
    const int tx = threadIdx.x, ty = threadIdx.y;
#pragma unroll
    for (int i = 0; i < 4; ++i)
        tile[ty + i * 8][tx] = src[(long)(kt * 32 + ty + i * 8) * N + nt * 32 + tx];
    __syncthreads();
#pragma unroll
    for (int i = 0; i < 4; ++i)
        dst[(long)(nt * 32 + ty + i * 8) * K + kt * 32 + tx] = (short)f2bf(tile[tx][ty + i * 8]);
}

// ---------------- bf16 MFMA GEMM: C[M,N] = A[M,K] @ BT[N,K]^T --------------
// 128x128 tile, BK=64, 4 waves (2x2), m97-style single-buffer 2-barrier loop.
template <int BIAS, int RELU, int OUTBF>
__global__ __launch_bounds__(256) void mm_kernel(const short* __restrict__ A,
                                                 const short* __restrict__ BT,
                                                 const float* __restrict__ bias,
                                                 void* __restrict__ Cv,
                                                 int N, int K) {
    __shared__ short As[128 * 64];
    __shared__ short Bs[128 * 64];
    const int tid = threadIdx.x;
    const int lane = tid & 63, wid = tid >> 6;
    const int wr = wid >> 1, wc = wid & 1;
    const int l15 = lane & 15, lhi = lane >> 4;
    const int row0 = blockIdx.y * 128, col0 = blockIdx.x * 128;

    f32x4 acc[4][4];
#pragma unroll
    for (int m = 0; m < 4; ++m)
#pragma unroll
        for (int n = 0; n < 4; ++n) acc[m][n] = zf4();

    const int nt = K >> 6;
    for (int t = 0; t < nt; ++t) {
        const int k0 = t << 6;
        {   // stage A,B tiles via global_load_lds (16B/lane)
#pragma unroll
            for (int c = 0; c < 4; ++c) {
                const int p = c * 4096 + tid * 16;
                const int row = p >> 7, cb = p & 127;
                const char* ga = (const char*)A + ((long)(row0 + row) * K + k0) * 2 + cb;
                const char* gb = (const char*)BT + ((long)(col0 + row) * K + k0) * 2 + cb;
                char* la = (char*)As + c * 4096 + (tid >> 6) * 1024;
                char* lb = (char*)Bs + c * 4096 + (tid >> 6) * 1024;
                __builtin_amdgcn_global_load_lds((gl_void*)ga, (lds_void*)la, 16, 0, 0);
                __builtin_amdgcn_global_load_lds((gl_void*)gb, (lds_void*)lb, 16, 0, 0);
            }
        }
        __syncthreads();
#pragma unroll
        for (int kk = 0; kk < 2; ++kk) {
            bf16x8 af[4], bf[4];
#pragma unroll
            for (int m = 0; m < 4; ++m)
                af[m] = *(const bf16x8*)(As + (wr * 64 + m * 16 + l15) * 64 + kk * 32 + lhi * 8);
#pragma unroll
            for (int n = 0; n < 4; ++n)
                bf[n] = *(const bf16x8*)(Bs + (wc * 64 + n * 16 + l15) * 64 + kk * 32 + lhi * 8);
#pragma unroll
            for (int m = 0; m < 4; ++m)
#pragma unroll
                for (int n = 0; n < 4; ++n)
                    acc[m][n] = __builtin_amdgcn_mfma_f32_16x16x32_bf16(af[m], bf[n], acc[m][n], 0, 0, 0);
        }
        __syncthreads();
    }

    float* Cf = (float*)Cv;
    short* Cb = (short*)Cv;
#pragma unroll
    for (int m = 0; m < 4; ++m) {
        const int r0 = row0 + wr * 64 + m * 16 + lhi * 4;
#pragma unroll
        for (int n = 0; n < 4; ++n) {
            const int cc = col0 + wc * 64 + n * 16 + l15;
            const float bv = BIAS ? bias[cc] : 0.f;
#pragma unroll
            for (int j = 0; j < 4; ++j) {
                float v = acc[m][n][j] + bv;
                if (RELU) v = fmaxf(v, 0.f);
                const long idx = (long)(r0 + j) * N + cc;
                if (OUTBF) Cb[idx] = (short)f2bf(v);
                else Cf[idx] = v;
            }
        }
    }
}

// ---------------- V transpose: qkv v-cols -> vT [B,H,64,S] bf16 -------------
__global__ __launch_bounds__(256) void vtr_kernel(const short* __restrict__ qkv,
                                                  short* __restrict__ vT) {
    __shared__ short tile[32][33];
    const int dt = blockIdx.x;   // 0..1
    const int st = blockIdx.y;   // 0..63
    const int bh = blockIdx.z;   // b*8+h
    const int b = bh >> 3, h = bh & 7;
    const int tx = threadIdx.x, ty = threadIdx.y;
    const short* src = qkv + ((long)b * TS + st * 32) * 1536 + 1024 + h * 64 + dt * 32;
#pragma unroll
    for (int i = 0; i < 4; ++i)
        tile[ty + i * 8][tx] = src[(long)(ty + i * 8) * 1536 + tx];
    __syncthreads();
    short* dst = vT + ((long)(bh * 64 + dt * 32)) * TS + st * 32;
#pragma unroll
    for (int i = 0; i < 4; ++i)
        dst[(long)(ty + i * 8) * TS + tx] = tile[tx][ty + i * 8];
}

// ---------------- bf16 MFMA flash attention ---------------------------------
// grid (S/64, H, B), 4 waves; wave owns 16 q-rows. K/V frags direct from L2.
__global__ __launch_bounds__(256) void attn_kernel(const short* __restrict__ qkv,
                                                   const short* __restrict__ vT,
                                                   short* __restrict__ ao) {
    __shared__ short Pl[4][16 * 64];
    const int qt = blockIdx.x, h = blockIdx.y, b = blockIdx.z;
    const int tid = threadIdx.x, lane = tid & 63, wid = tid >> 6;
    const int l15 = lane & 15, lhi = lane >> 4;

    const long rq = (long)b * TS + qt * 64 + wid * 16 + l15;
    bf16x8 qa0 = *(const bf16x8*)(qkv + rq * 1536 + h * 64 + lhi * 8);
    bf16x8 qa1 = *(const bf16x8*)(qkv + rq * 1536 + h * 64 + 32 + lhi * 8);

    f32x4 o[4];
    float m_run[4], l_run[4];
#pragma unroll
    for (int n = 0; n < 4; ++n) o[n] = zf4();
#pragma unroll
    for (int j = 0; j < 4; ++j) { m_run[j] = -1e30f; l_run[j] = 0.f; }

    char* pl = (char*)&Pl[wid][0];
    const short* kbase = qkv + ((long)b * TS) * 1536 + 512 + h * 64;
    const short* vbase = vT + ((long)(b * 8 + h) * 64) * TS;

    for (int kt = 0; kt < TS / 64; ++kt) {
        // ---- S = (Q @ K^T) * 1/8 ----
        f32x4 s[4];
#pragma unroll
        for (int cf = 0; cf < 4; ++cf) {
            const short* kr = kbase + (long)(kt * 64 + cf * 16 + l15) * 1536;
            bf16x8 k0 = *(const bf16x8*)(kr + lhi * 8);
            bf16x8 k1 = *(const bf16x8*)(kr + 32 + lhi * 8);
            f32x4 z = zf4();
            z = __builtin_amdgcn_mfma_f32_16x16x32_bf16(qa0, k0, z, 0, 0, 0);
            s[cf] = __builtin_amdgcn_mfma_f32_16x16x32_bf16(qa1, k1, z, 0, 0, 0);
        }
        // ---- online softmax per owned q-row (j) ----
#pragma unroll
        for (int j = 0; j < 4; ++j) {
            float v0 = s[0][j] * 0.125f, v1 = s[1][j] * 0.125f;
            float v2 = s[2][j] * 0.125f, v3 = s[3][j] * 0.125f;
            float rm = fmaxf(fmaxf(v0, v1), fmaxf(v2, v3));
            rm = fmaxf(rm, __shfl_xor(rm, 1, 64));
            rm = fmaxf(rm, __shfl_xor(rm, 2, 64));
            rm = fmaxf(rm, __shfl_xor(rm, 4, 64));
            rm = fmaxf(rm, __shfl_xor(rm, 8, 64));
            const float mnew = fmaxf(m_run[j], rm);
            const float p0 = __expf(v0 - mnew), p1 = __expf(v1 - mnew);
            const float p2 = __expf(v2 - mnew), p3 = __expf(v3 - mnew);
            float rs = p0 + p1 + p2 + p3;
            rs += __shfl_xor(rs, 1, 64);
            rs += __shfl_xor(rs, 2, 64);
            rs += __shfl_xor(rs, 4, 64);
            rs += __shfl_xor(rs, 8, 64);
            const float scl = __expf(m_run[j] - mnew);
            l_run[j] = l_run[j] * scl + rs;
            m_run[j] = mnew;
            o[0][j] *= scl; o[1][j] *= scl; o[2][j] *= scl; o[3][j] *= scl;
            // store P row q = lhi*4+j (bf16, XOR-swizzled)
            const int q = lhi * 4 + j;
            const int sw = (q & 7) << 4;
            *(short*)(pl + ((q * 128 + (0 * 16 + l15) * 2) ^ sw)) = (short)f2bf(p0);
            *(short*)(pl + ((q * 128 + (1 * 16 + l15) * 2) ^ sw)) = (short)f2bf(p1);
            *(short*)(pl + ((q * 128 + (2 * 16 + l15) * 2) ^ sw)) = (short)f2bf(p2);
            *(short*)(pl + ((q * 128 + (3 * 16 + l15) * 2) ^ sw)) = (short)f2bf(p3);
        }
        __syncthreads();
        // ---- O += P @ V ----
        bf16x8 pa0, pa1;
        {
            const int q = l15, sw = (q & 7) << 4;
            pa0 = *(const bf16x8*)(pl + ((q * 128 + lhi * 16) ^ sw));
            pa1 = *(const bf16x8*)(pl + ((q * 128 + 64 + lhi * 16) ^ sw));
        }
#pragma unroll
        for (int n = 0; n < 4; ++n) {
            const short* vr = vbase + (long)(n * 16 + l15) * TS + kt * 64;
            bf16x8 v0 = *(const bf16x8*)(vr + lhi * 8);
            bf16x8 v1 = *(const bf16x8*)(vr + 32 + lhi * 8);
            o[n] = __builtin_amdgcn_mfma_f32_16x16x32_bf16(pa0, v0, o[n], 0, 0, 0);
            o[n] = __builtin_amdgcn_mfma_f32_16x16x32_bf16(pa1, v1, o[n], 0, 0, 0);
        }
    }

    const long orow0 = (long)b * TS + qt * 64 + wid * 16 + lhi * 4;
#pragma unroll
    for (int n = 0; n < 4; ++n) {
        const int cc = h * 64 + n * 16 + l15;
#pragma unroll
        for (int j = 0; j < 4; ++j) {
            const float v = o[n][j] / l_run[j];
            ao[(orow0 + j) * TD + cc] = (short)f2bf(v);
        }
    }
}

// ---------------- fused residual-add + LayerNorm (fp32 + bf16 copy) ---------
__global__ __launch_bounds__(64) void addln_kernel(const float* __restrict__ a,
                                                   const float* __restrict__ res,
                                                   const float* __restrict__ g,
                                                   const float* __restrict__ bt,
                                                   float* __restrict__ out,
                                                   short* __restrict__ outb) {
    const int row = blockIdx.x;
    const int d0 = threadIdx.x * 8;
    const float* pa = a + (long)row * TD + d0;
    const float* pr = res + (long)row * TD + d0;
    float v[8];
    const float4 a0 = *(const float4*)pa, a1 = *(const float4*)(pa + 4);
    const float4 r0 = *(const float4*)pr, r1 = *(const float4*)(pr + 4);
    v[0] = a0.x + r0.x; v[1] = a0.y + r0.y; v[2] = a0.z + r0.z; v[3] = a0.w + r0.w;
    v[4] = a1.x + r1.x; v[5] = a1.y + r1.y; v[6] = a1.z + r1.z; v[7] = a1.w + r1.w;
    float s = 0.f, s2 = 0.f;
#pragma unroll
    for (int j = 0; j < 8; ++j) { s += v[j]; s2 += v[j] * v[j]; }
#pragma unroll
    for (int m = 1; m < 64; m <<= 1) {
        s += __shfl_xor(s, m, 64);
        s2 += __shfl_xor(s2, m, 64);
    }
    const float mean = s * (1.f / TD);
    const float var = s2 * (1.f / TD) - mean * mean;
    const float rstd = rsqrtf(var + TEPS);
    const float* pg = g + d0;
    const float* pb = bt + d0;
    float ov[8];
#pragma unroll
    for (int j = 0; j < 8; ++j) ov[j] = (v[j] - mean) * rstd * pg[j] + pb[j];
    float* po = out + (long)row * TD + d0;
    float4 o0, o1;
    o0.x = ov[0]; o0.y = ov[1]; o0.z = ov[2]; o0.w = ov[3];
    o1.x = ov[4]; o1.y = ov[5]; o1.z = ov[6]; o1.w = ov[7];
    *(float4*)po = o0;
    *(float4*)(po + 4) = o1;
    if (outb) {
        bf16x8 t;
#pragma unroll
        for (int j = 0; j < 8; ++j) t[j] = (short)f2bf(ov[j]);
        *(bf16x8*)(outb + (long)row * TD + d0) = t;
    }
}

extern "C" void kernel_launch(void* const* d_in, const int* in_sizes, int n_in,
                              void* d_out, int out_size, void* d_ws, size_t ws_size,
                              hipStream_t stream) {
    const int* tokens = (const int*)d_in[0];
    const float* emb = (const float*)d_in[1];
    const float* wq = (const float*)d_in[2];
    const float* wk = (const float*)d_in[3];
    const float* wv = (const float*)d_in[4];
    const float* wo = (const float*)d_in[5];
    const float* w1 = (const float*)d_in[6];
    const float* b1 = (const float*)d_in[7];
    const float* w2 = (const float*)d_in[8];
    const float* b2 = (const float*)d_in[9];
    const float* g1 = (const float*)d_in[10];
    const float* be1 = (const float*)d_in[11];
    const float* g2 = (const float*)d_in[12];
    const float* be2 = (const float*)d_in[13];

    float* ws = (float*)d_ws;
    float* x = ws;                         // f32 residual stream [M,512]
    float* tmp = ws + ND;                  // f32 gemm output [M,512]
    short* sb = (short*)(ws + 2 * ND);
    short* xb = sb;                        // bf16 x copy       (2,097,152)
    short* share = sb + ND;                // shared region     (8,388,608)
    short* qkv = share;                    //   [M,1536]        (6,291,456)
    short* vTb = share + (long)4096 * 1536;//   [B,H,64,S]      (2,097,152)
    short* ff = share;                     //   [M,2048] (FF phase)
    short* aob = share + 8388608;          // attn out bf16     (2,097,152)
    short* wT = aob + ND;                  // weights           (3,145,728)
    short* qkvT = wT;
    short* woT = qkvT + 1536 * 512;
    short* w1T = woT + 512 * 512;
    short* w2T = w1T + 2048 * 512;
    float* out = (float*)d_out;

    embed_kernel<<<NBS, 64, 0, stream>>>(tokens, emb, x, xb);

    const dim3 blk256(256);
    const dim3 blkT(32, 8);
    const dim3 gQKV(1536 / 128, NBS / 128);  // (12, 32)
    const dim3 gD(512 / 128, NBS / 128);     // (4, 32)
    const dim3 gF(2048 / 128, NBS / 128);    // (16, 32)
    const dim3 gA(TS / 64, TH, TB);          // (32, 8, 2)
    const dim3 gV(2, TS / 32, TB * TH);      // (2, 64, 16)

    for (int l = 0; l < TL; ++l) {
        wprep_kernel<<<3072, blkT, 0, stream>>>(wq, wk, wv, wo, w1, w2, l, qkvT, woT, w1T, w2T);
        mm_kernel<0, 0, 1><<<gQKV, blk256, 0, stream>>>(xb, qkvT, nullptr, qkv, 1536, 512);
        vtr_kernel<<<gV, blkT, 0, stream>>>(qkv, vTb);
        attn_kernel<<<gA, blk256, 0, stream>>>(qkv, vTb, aob);
        mm_kernel<0, 0, 0><<<gD, blk256, 0, stream>>>(aob, woT, nullptr, tmp, 512, 512);
        addln_kernel<<<NBS, 64, 0, stream>>>(tmp, x, g1 + (long)l * TD, be1 + (long)l * TD, x, xb);
        mm_kernel<1, 1, 1><<<gF, blk256, 0, stream>>>(xb, w1T, b1 + (long)l * TF, ff, 2048, 512);
        mm_kernel<1, 0, 0><<<gD, blk256, 0, stream>>>(ff, w2T, b2 + (long)l * TD, tmp, 512, 2048);
        if (l == TL - 1) {
            addln_kernel<<<NBS, 64, 0, stream>>>(tmp, x, g2 + (long)l * TD, be2 + (long)l * TD, out, nullptr);
        } else {
            addln_kernel<<<NBS, 64, 0, stream>>>(tmp, x, g2 + (long)l * TD, be2 + (long)l * TD, x, xb);
        }
    }
}

// Round 4
// 778.621 us; speedup vs baseline: 4.1984x; 1.5343x over previous
//
#include <hip/hip_runtime.h>
#include <math.h>

#define TV 32000
#define TD 512
#define TS 2048
#define TH 8
#define TF 2048
#define TL 4
#define TB 2
#define THD 64
#define TEPS 1e-5f
#define NBS (TB * TS)               // 4096 token rows
#define ND ((long)NBS * TD)         // 2097152 elements per activation buffer

typedef short bf16x8 __attribute__((ext_vector_type(8)));
typedef short bf16x4 __attribute__((ext_vector_type(4)));
typedef float f32x4 __attribute__((ext_vector_type(4)));
typedef __attribute__((address_space(3))) void lds_void;
typedef const __attribute__((address_space(1))) void gl_void;

__device__ __forceinline__ unsigned short f2bf(float f) {
    unsigned u = __builtin_bit_cast(unsigned, f);
    unsigned r = (u + 0x7fffu + ((u >> 16) & 1u)) >> 16;
    return (unsigned short)r;
}

__device__ __forceinline__ f32x4 zf4() {
    f32x4 z = {0.f, 0.f, 0.f, 0.f};
    return z;
}

// ---------------- embedding + sinusoidal positional encoding ----------------
__global__ __launch_bounds__(64) void embed_kernel(const int* __restrict__ tokens,
                                                   const float* __restrict__ emb,
                                                   float* __restrict__ x,
                                                   short* __restrict__ xb) {
    const int bs = blockIdx.x;
    const int s = bs & (TS - 1);
    const int tok = tokens[bs];
    const float* e = emb + (long)tok * TD;
    const int d0 = threadIdx.x * 8;
    float v[8];
#pragma unroll
    for (int j = 0; j < 8; ++j) {
        const int d = d0 + j;
        const float div = expf((float)(d & ~1) * (-9.210340371976184f / (float)TD));
        const float ang = (float)s * div;
        const float pe = (d & 1) ? cosf(ang) : sinf(ang);
        v[j] = e[d] + pe;
    }
    float* xo = x + (long)bs * TD + d0;
    float4 o0, o1;
    o0.x = v[0]; o0.y = v[1]; o0.z = v[2]; o0.w = v[3];
    o1.x = v[4]; o1.y = v[5]; o1.z = v[6]; o1.w = v[7];
    *(float4*)xo = o0;
    *(float4*)(xo + 4) = o1;
    bf16x8 t;
#pragma unroll
    for (int j = 0; j < 8; ++j) t[j] = (short)f2bf(v[j]);
    *(bf16x8*)(xb + (long)bs * TD + d0) = t;
}

// ---------------- weight prep: fp32 [K,N] -> bf16 [N,K], all 6 mats/layer ---
__global__ __launch_bounds__(256) void wprep_kernel(const float* __restrict__ wq,
                                                    const float* __restrict__ wk,
                                                    const float* __restrict__ wv,
                                                    const float* __restrict__ wo,
                                                    const float* __restrict__ w1,
                                                    const float* __restrict__ w2,
                                                    int l,
                                                    short* __restrict__ qkvT,
                                                    short* __restrict__ woT,
                                                    short* __restrict__ w1T,
                                                    short* __restrict__ w2T) {
    __shared__ float tile[32][33];
    const int t = blockIdx.x;
    const float* src;
    short* dst;
    int K, N, kt, nt;
    if (t < 1024) {
        const int mat = t >> 8, tt = t & 255;
        kt = tt >> 4; nt = tt & 15; K = 512; N = 512;
        const float* s4 = (mat == 0) ? wq : (mat == 1) ? wk : (mat == 2) ? wv : wo;
        src = s4 + (long)l * 512 * 512;
        dst = (mat < 3) ? qkvT + mat * 512 * 512 : woT;
    } else if (t < 2048) {
        const int tt = t - 1024;
        kt = tt & 15; nt = tt >> 4; K = 512; N = 2048;
        src = w1 + (long)l * 512 * 2048; dst = w1T;
    } else {
        const int tt = t - 2048;
        kt = tt >> 4; nt = tt & 15; K = 2048; N = 512;
        src = w2 + (long)l * 2048 * 512; dst = w2T;
    }
    const int tx = threadIdx.x, ty = threadIdx.y;
#pragma unroll
    for (int i = 0; i < 4; ++i)
        tile[ty + i * 8][tx] = src[(long)(kt * 32 + ty + i * 8) * N + nt * 32 + tx];
    __syncthreads();
#pragma unroll
    for (int i = 0; i < 4; ++i)
        dst[(long)(nt * 32 + ty + i * 8) * K + kt * 32 + tx] = (short)f2bf(tile[tx][ty + i * 8]);
}

// ---------------- bf16 MFMA GEMM: C[M,N] = A[M,K] @ BT[N,K]^T --------------
template <int BIAS, int RELU, int OUTBF>
__global__ __launch_bounds__(256) void mm_kernel(const short* __restrict__ A,
                                                 const short* __restrict__ BT,
                                                 const float* __restrict__ bias,
                                                 void* __restrict__ Cv,
                                                 int N, int K) {
    __shared__ short As[128 * 64];
    __shared__ short Bs[128 * 64];
    const int tid = threadIdx.x;
    const int lane = tid & 63, wid = tid >> 6;
    const int wr = wid >> 1, wc = wid & 1;
    const int l15 = lane & 15, lhi = lane >> 4;
    const int row0 = blockIdx.y * 128, col0 = blockIdx.x * 128;

    f32x4 acc[4][4];
#pragma unroll
    for (int m = 0; m < 4; ++m)
#pragma unroll
        for (int n = 0; n < 4; ++n) acc[m][n] = zf4();

    const int nt = K >> 6;
    for (int t = 0; t < nt; ++t) {
        const int k0 = t << 6;
        {
#pragma unroll
            for (int c = 0; c < 4; ++c) {
                const int p = c * 4096 + tid * 16;
                const int row = p >> 7, cb = p & 127;
                const char* ga = (const char*)A + ((long)(row0 + row) * K + k0) * 2 + cb;
                const char* gb = (const char*)BT + ((long)(col0 + row) * K + k0) * 2 + cb;
                char* la = (char*)As + c * 4096 + (tid >> 6) * 1024;
                char* lb = (char*)Bs + c * 4096 + (tid >> 6) * 1024;
                __builtin_amdgcn_global_load_lds((gl_void*)ga, (lds_void*)la, 16, 0, 0);
                __builtin_amdgcn_global_load_lds((gl_void*)gb, (lds_void*)lb, 16, 0, 0);
            }
        }
        __syncthreads();
#pragma unroll
        for (int kk = 0; kk < 2; ++kk) {
            bf16x8 af[4], bf[4];
#pragma unroll
            for (int m = 0; m < 4; ++m)
                af[m] = *(const bf16x8*)(As + (wr * 64 + m * 16 + l15) * 64 + kk * 32 + lhi * 8);
#pragma unroll
            for (int n = 0; n < 4; ++n)
                bf[n] = *(const bf16x8*)(Bs + (wc * 64 + n * 16 + l15) * 64 + kk * 32 + lhi * 8);
#pragma unroll
            for (int m = 0; m < 4; ++m)
#pragma unroll
                for (int n = 0; n < 4; ++n)
                    acc[m][n] = __builtin_amdgcn_mfma_f32_16x16x32_bf16(af[m], bf[n], acc[m][n], 0, 0, 0);
        }
        __syncthreads();
    }

    float* Cf = (float*)Cv;
    short* Cb = (short*)Cv;
#pragma unroll
    for (int m = 0; m < 4; ++m) {
        const int r0 = row0 + wr * 64 + m * 16 + lhi * 4;
#pragma unroll
        for (int n = 0; n < 4; ++n) {
            const int cc = col0 + wc * 64 + n * 16 + l15;
            const float bv = BIAS ? bias[cc] : 0.f;
#pragma unroll
            for (int j = 0; j < 4; ++j) {
                float v = acc[m][n][j] + bv;
                if (RELU) v = fmaxf(v, 0.f);
                const long idx = (long)(r0 + j) * N + cc;
                if (OUTBF) Cb[idx] = (short)f2bf(v);
                else Cf[idx] = v;
            }
        }
    }
}

// ---------------- V transpose: qkv v-cols -> vT [B,H,64,S] bf16 -------------
__global__ __launch_bounds__(256) void vtr_kernel(const short* __restrict__ qkv,
                                                  short* __restrict__ vT) {
    __shared__ short tile[32][33];
    const int dt = blockIdx.x;
    const int st = blockIdx.y;
    const int bh = blockIdx.z;
    const int b = bh >> 3, h = bh & 7;
    const int tx = threadIdx.x, ty = threadIdx.y;
    const short* src = qkv + ((long)b * TS + st * 32) * 1536 + 1024 + h * 64 + dt * 32;
#pragma unroll
    for (int i = 0; i < 4; ++i)
        tile[ty + i * 8][tx] = src[(long)(ty + i * 8) * 1536 + tx];
    __syncthreads();
    short* dst = vT + ((long)(bh * 64 + dt * 32)) * TS + st * 32;
#pragma unroll
    for (int i = 0; i < 4; ++i)
        dst[(long)(ty + i * 8) * TS + tx] = tile[tx][ty + i * 8];
}

// ---------------- bf16 MFMA flash attention (swapped QK^T, LDS-staged K/V) --
// 1D grid 512 blocks, XCD-swizzled. 4 waves/block; wave owns 16 q-rows.
__global__ __launch_bounds__(256) void attn_kernel(const short* __restrict__ qkv,
                                                   const short* __restrict__ vT,
                                                   short* __restrict__ ao) {
    __shared__ short Ks[2][4096];   // [buf] 64 rows x 128B, XOR-swizzled
    __shared__ short Vs[2][4096];   // [buf] V^T: 64 d-rows x 128B (64 k), swizzled
    __shared__ short Ps[4][1024];   // per-wave P [16 q][64 k], swizzled

    const int orig = blockIdx.x;
    const int wgid = (orig & 7) * 64 + (orig >> 3);   // XCD gets contiguous chunk
    const int qt = wgid & 31;
    const int bh = wgid >> 5;
    const int b = bh >> 3, h = bh & 7;
    const int tid = threadIdx.x, lane = tid & 63, wid = tid >> 6;
    const int l15 = lane & 15, lhi = lane >> 4;

    const long rq = (long)b * TS + qt * 64 + wid * 16 + l15;
    const bf16x8 qa0 = *(const bf16x8*)(qkv + rq * 1536 + h * 64 + lhi * 8);
    const bf16x8 qa1 = *(const bf16x8*)(qkv + rq * 1536 + h * 64 + 32 + lhi * 8);

    const char* kbase = (const char*)(qkv + ((long)b * TS) * 1536 + 512 + h * 64);
    const char* vbase = (const char*)(vT + ((long)(bh * 64)) * TS);

    const int rr = wid * 8 + (lane >> 3);                 // staging row within 32-band
    const int cswz = 16 * ((lane & 7) ^ (lane >> 3));     // pre-swizzled source col

    f32x4 o[4];
#pragma unroll
    for (int n = 0; n < 4; ++n) o[n] = zf4();
    float m_run = -1e30f, l_run = 0.f;

    // prologue stage kt=0 into buf 0
#pragma unroll
    for (int i = 0; i < 2; ++i) {
        const char* gk = kbase + (long)(i * 32 + rr) * 3072 + cswz;
        const char* gv = vbase + (long)(i * 32 + rr) * (TS * 2) + cswz;
        char* lk = (char*)&Ks[0][0] + i * 4096 + wid * 1024;
        char* lv = (char*)&Vs[0][0] + i * 4096 + wid * 1024;
        __builtin_amdgcn_global_load_lds((gl_void*)gk, (lds_void*)lk, 16, 0, 0);
        __builtin_amdgcn_global_load_lds((gl_void*)gv, (lds_void*)lv, 16, 0, 0);
    }
    __syncthreads();

    const int sw = (l15 & 7) << 4;
    char* pl = (char*)&Ps[wid][0];
    int cur = 0;

    for (int kt = 0; kt < TS / 64; ++kt) {
        // prefetch next tile into other buffer
        if (kt + 1 < TS / 64) {
#pragma unroll
            for (int i = 0; i < 2; ++i) {
                const char* gk = kbase + (long)((kt + 1) * 64 + i * 32 + rr) * 3072 + cswz;
                const char* gv = vbase + (long)(i * 32 + rr) * (TS * 2) + (kt + 1) * 128 + cswz;
                char* lk = (char*)&Ks[cur ^ 1][0] + i * 4096 + wid * 1024;
                char* lv = (char*)&Vs[cur ^ 1][0] + i * 4096 + wid * 1024;
                __builtin_amdgcn_global_load_lds((gl_void*)gk, (lds_void*)lk, 16, 0, 0);
                __builtin_amdgcn_global_load_lds((gl_void*)gv, (lds_void*)lv, 16, 0, 0);
            }
        }

        // ---- S^T = K @ Q^T : lane owns q-row l15, k = cf*16 + lhi*4 + j ----
        const char* kl = (const char*)&Ks[cur][0];
        f32x4 s[4];
        __builtin_amdgcn_s_setprio(1);
#pragma unroll
        for (int cf = 0; cf < 4; ++cf) {
            const int row = cf * 16 + l15;
            const bf16x8 k0 = *(const bf16x8*)(kl + row * 128 + ((lhi * 16) ^ sw));
            const bf16x8 k1 = *(const bf16x8*)(kl + row * 128 + ((64 + lhi * 16) ^ sw));
            f32x4 z = zf4();
            z = __builtin_amdgcn_mfma_f32_16x16x32_bf16(k0, qa0, z, 0, 0, 0);
            s[cf] = __builtin_amdgcn_mfma_f32_16x16x32_bf16(k1, qa1, z, 0, 0, 0);
        }
        __builtin_amdgcn_s_setprio(0);

        // ---- online softmax: lane-local 16 values + 2 shfl ----
        float pv[16];
        float rm = -1e30f;
#pragma unroll
        for (int cf = 0; cf < 4; ++cf)
#pragma unroll
            for (int j = 0; j < 4; ++j) {
                const float v = s[cf][j] * 0.125f;
                pv[cf * 4 + j] = v;
                rm = fmaxf(rm, v);
            }
        rm = fmaxf(rm, __shfl_xor(rm, 16, 64));
        rm = fmaxf(rm, __shfl_xor(rm, 32, 64));
        const float mnew = fmaxf(m_run, rm);
        float rs = 0.f;
#pragma unroll
        for (int i = 0; i < 16; ++i) { pv[i] = __expf(pv[i] - mnew); rs += pv[i]; }
        rs += __shfl_xor(rs, 16, 64);
        rs += __shfl_xor(rs, 32, 64);
        const float scl = __expf(m_run - mnew);
        l_run = l_run * scl + rs;
        m_run = mnew;

        // rescale O (rows q = lhi*4+j) with scl from lane l15 = q
        const float s0 = __shfl(scl, lhi * 4 + 0, 64);
        const float s1 = __shfl(scl, lhi * 4 + 1, 64);
        const float s2 = __shfl(scl, lhi * 4 + 2, 64);
        const float s3 = __shfl(scl, lhi * 4 + 3, 64);
#pragma unroll
        for (int n = 0; n < 4; ++n) {
            o[n][0] *= s0; o[n][1] *= s1; o[n][2] *= s2; o[n][3] *= s3;
        }

        // ---- write P (bf16) to per-wave LDS, row q = l15 ----
#pragma unroll
        for (int cf = 0; cf < 4; ++cf) {
            bf16x4 pk;
            pk[0] = (short)f2bf(pv[cf * 4 + 0]);
            pk[1] = (short)f2bf(pv[cf * 4 + 1]);
            pk[2] = (short)f2bf(pv[cf * 4 + 2]);
            pk[3] = (short)f2bf(pv[cf * 4 + 3]);
            *(bf16x4*)(pl + l15 * 128 + ((cf * 32 + lhi * 8) ^ sw)) = pk;
        }
        asm volatile("s_waitcnt lgkmcnt(0)" ::: "memory");
        __builtin_amdgcn_sched_barrier(0);

        // ---- O += P @ V (wave-local P, staged V^T) ----
        const bf16x8 pa0 = *(const bf16x8*)(pl + l15 * 128 + ((lhi * 16) ^ sw));
        const bf16x8 pa1 = *(const bf16x8*)(pl + l15 * 128 + ((64 + lhi * 16) ^ sw));
        const char* vl = (const char*)&Vs[cur][0];
        __builtin_amdgcn_s_setprio(1);
#pragma unroll
        for (int n = 0; n < 4; ++n) {
            const int row = n * 16 + l15;
            const bf16x8 v0 = *(const bf16x8*)(vl + row * 128 + ((lhi * 16) ^ sw));
            const bf16x8 v1 = *(const bf16x8*)(vl + row * 128 + ((64 + lhi * 16) ^ sw));
            o[n] = __builtin_amdgcn_mfma_f32_16x16x32_bf16(pa0, v0, o[n], 0, 0, 0);
            o[n] = __builtin_amdgcn_mfma_f32_16x16x32_bf16(pa1, v1, o[n], 0, 0, 0);
        }
        __builtin_amdgcn_s_setprio(0);
        __syncthreads();   // all waves done with K/V[cur] + staging loads landed
        cur ^= 1;
    }

    float invl[4];
#pragma unroll
    for (int j = 0; j < 4; ++j) invl[j] = 1.f / __shfl(l_run, lhi * 4 + j, 64);
    const long orow0 = (long)b * TS + qt * 64 + wid * 16 + lhi * 4;
#pragma unroll
    for (int n = 0; n < 4; ++n) {
        const int cc = h * 64 + n * 16 + l15;
#pragma unroll
        for (int j = 0; j < 4; ++j) {
            const float v = o[n][j] * invl[j];
            ao[(orow0 + j) * TD + cc] = (short)f2bf(v);
        }
    }
}

// ---------------- fused residual-add + LayerNorm (4 rows per block) ---------
__global__ __launch_bounds__(256) void addln_kernel(const float* __restrict__ a,
                                                    const float* __restrict__ res,
                                                    const float* __restrict__ g,
                                                    const float* __restrict__ bt,
                                                    float* __restrict__ out,
                                                    short* __restrict__ outb) {
    const int row = blockIdx.x * 4 + threadIdx.y;
    const int d0 = threadIdx.x * 8;
    const float* pa = a + (long)row * TD + d0;
    const float* pr = res + (long)row * TD + d0;
    float v[8];
    const float4 a0 = *(const float4*)pa, a1 = *(const float4*)(pa + 4);
    const float4 r0 = *(const float4*)pr, r1 = *(const float4*)(pr + 4);
    v[0] = a0.x + r0.x; v[1] = a0.y + r0.y; v[2] = a0.z + r0.z; v[3] = a0.w + r0.w;
    v[4] = a1.x + r1.x; v[5] = a1.y + r1.y; v[6] = a1.z + r1.z; v[7] = a1.w + r1.w;
    float s = 0.f, s2 = 0.f;
#pragma unroll
    for (int j = 0; j < 8; ++j) { s += v[j]; s2 += v[j] * v[j]; }
#pragma unroll
    for (int m = 1; m < 64; m <<= 1) {
        s += __shfl_xor(s, m, 64);
        s2 += __shfl_xor(s2, m, 64);
    }
    const float mean = s * (1.f / TD);
    const float var = s2 * (1.f / TD) - mean * mean;
    const float rstd = rsqrtf(var + TEPS);
    const float* pg = g + d0;
    const float* pb = bt + d0;
    float ov[8];
#pragma unroll
    for (int j = 0; j < 8; ++j) ov[j] = (v[j] - mean) * rstd * pg[j] + pb[j];
    float* po = out + (long)row * TD + d0;
    float4 o0, o1;
    o0.x = ov[0]; o0.y = ov[1]; o0.z = ov[2]; o0.w = ov[3];
    o1.x = ov[4]; o1.y = ov[5]; o1.z = ov[6]; o1.w = ov[7];
    *(float4*)po = o0;
    *(float4*)(po + 4) = o1;
    if (outb) {
        bf16x8 t;
#pragma unroll
        for (int j = 0; j < 8; ++j) t[j] = (short)f2bf(ov[j]);
        *(bf16x8*)(outb + (long)row * TD + d0) = t;
    }
}

extern "C" void kernel_launch(void* const* d_in, const int* in_sizes, int n_in,
                              void* d_out, int out_size, void* d_ws, size_t ws_size,
                              hipStream_t stream) {
    const int* tokens = (const int*)d_in[0];
    const float* emb = (const float*)d_in[1];
    const float* wq = (const float*)d_in[2];
    const float* wk = (const float*)d_in[3];
    const float* wv = (const float*)d_in[4];
    const float* wo = (const float*)d_in[5];
    const float* w1 = (const float*)d_in[6];
    const float* b1 = (const float*)d_in[7];
    const float* w2 = (const float*)d_in[8];
    const float* b2 = (const float*)d_in[9];
    const float* g1 = (const float*)d_in[10];
    const float* be1 = (const float*)d_in[11];
    const float* g2 = (const float*)d_in[12];
    const float* be2 = (const float*)d_in[13];

    float* ws = (float*)d_ws;
    float* x = ws;                         // f32 residual stream [M,512]
    float* tmp = ws + ND;                  // f32 gemm output [M,512]
    short* sb = (short*)(ws + 2 * ND);
    short* xb = sb;                        // bf16 x copy
    short* share = sb + ND;
    short* qkv = share;                    // [M,1536]
    short* vTb = share + (long)4096 * 1536;// [B,H,64,S]
    short* ff = share;                     // [M,2048] (FF phase)
    short* aob = share + 8388608;          // attn out bf16
    short* wT = aob + ND;
    short* qkvT = wT;
    short* woT = qkvT + 1536 * 512;
    short* w1T = woT + 512 * 512;
    short* w2T = w1T + 2048 * 512;
    float* out = (float*)d_out;

    embed_kernel<<<NBS, 64, 0, stream>>>(tokens, emb, x, xb);

    const dim3 blk256(256);
    const dim3 blkT(32, 8);
    const dim3 blkLN(64, 4);
    const dim3 gQKV(1536 / 128, NBS / 128);
    const dim3 gD(512 / 128, NBS / 128);
    const dim3 gF(2048 / 128, NBS / 128);
    const dim3 gV(2, TS / 32, TB * TH);

    for (int l = 0; l < TL; ++l) {
        wprep_kernel<<<3072, blkT, 0, stream>>>(wq, wk, wv, wo, w1, w2, l, qkvT, woT, w1T, w2T);
        mm_kernel<0, 0, 1><<<gQKV, blk256, 0, stream>>>(xb, qkvT, nullptr, qkv, 1536, 512);
        vtr_kernel<<<gV, blkT, 0, stream>>>(qkv, vTb);
        attn_kernel<<<512, blk256, 0, stream>>>(qkv, vTb, aob);
        mm_kernel<0, 0, 0><<<gD, blk256, 0, stream>>>(aob, woT, nullptr, tmp, 512, 512);
        addln_kernel<<<NBS / 4, blkLN, 0, stream>>>(tmp, x, g1 + (long)l * TD, be1 + (long)l * TD, x, xb);
        mm_kernel<1, 1, 1><<<gF, blk256, 0, stream>>>(xb, w1T, b1 + (long)l * TF, ff, 2048, 512);
        mm_kernel<1, 0, 0><<<gD, blk256, 0, stream>>>(ff, w2T, b2 + (long)l * TD, tmp, 512, 2048);
        if (l == TL - 1) {
            addln_kernel<<<NBS / 4, blkLN, 0, stream>>>(tmp, x, g2 + (long)l * TD, be2 + (long)l * TD, out, nullptr);
        } else {
            addln_kernel<<<NBS / 4, blkLN, 0, stream>>>(tmp, x, g2 + (long)l * TD, be2 + (long)l * TD, x, xb);
        }
    }
}

// Round 5
// 732.996 us; speedup vs baseline: 4.4598x; 1.0622x over previous
//
#include <hip/hip_runtime.h>
#include <math.h>

#define TV 32000
#define TD 512
#define TS 2048
#define TH 8
#define TF 2048
#define TL 4
#define TB 2
#define THD 64
#define TEPS 1e-5f
#define NBS (TB * TS)               // 4096 token rows
#define ND ((long)NBS * TD)         // 2097152 elements per activation buffer

typedef short bf16x8 __attribute__((ext_vector_type(8)));
typedef short bf16x4 __attribute__((ext_vector_type(4)));
typedef float f32x4 __attribute__((ext_vector_type(4)));
typedef __attribute__((address_space(3))) void lds_void;
typedef const __attribute__((address_space(1))) void gl_void;

__device__ __forceinline__ unsigned short f2bf(float f) {
    unsigned u = __builtin_bit_cast(unsigned, f);
    unsigned r = (u + 0x7fffu + ((u >> 16) & 1u)) >> 16;
    return (unsigned short)r;
}

__device__ __forceinline__ f32x4 zf4() {
    f32x4 z = {0.f, 0.f, 0.f, 0.f};
    return z;
}

// ---------------- embedding + sinusoidal positional encoding ----------------
__global__ __launch_bounds__(64) void embed_kernel(const int* __restrict__ tokens,
                                                   const float* __restrict__ emb,
                                                   float* __restrict__ x,
                                                   short* __restrict__ xb) {
    const int bs = blockIdx.x;
    const int s = bs & (TS - 1);
    const int tok = tokens[bs];
    const float* e = emb + (long)tok * TD;
    const int d0 = threadIdx.x * 8;
    float v[8];
#pragma unroll
    for (int j = 0; j < 8; ++j) {
        const int d = d0 + j;
        const float div = expf((float)(d & ~1) * (-9.210340371976184f / (float)TD));
        const float ang = (float)s * div;
        const float pe = (d & 1) ? cosf(ang) : sinf(ang);
        v[j] = e[d] + pe;
    }
    float* xo = x + (long)bs * TD + d0;
    float4 o0, o1;
    o0.x = v[0]; o0.y = v[1]; o0.z = v[2]; o0.w = v[3];
    o1.x = v[4]; o1.y = v[5]; o1.z = v[6]; o1.w = v[7];
    *(float4*)xo = o0;
    *(float4*)(xo + 4) = o1;
    bf16x8 t;
#pragma unroll
    for (int j = 0; j < 8; ++j) t[j] = (short)f2bf(v[j]);
    *(bf16x8*)(xb + (long)bs * TD + d0) = t;
}

// ---------------- weight prep: fp32 [K,N] -> bf16 [N,K], all 6 mats/layer ---
__global__ __launch_bounds__(256) void wprep_kernel(const float* __restrict__ wq,
                                                    const float* __restrict__ wk,
                                                    const float* __restrict__ wv,
                                                    const float* __restrict__ wo,
                                                    const float* __restrict__ w1,
                                                    const float* __restrict__ w2,
                                                    int l,
                                                    short* __restrict__ qkvT,
                                                    short* __restrict__ woT,
                                                    short* __restrict__ w1T,
                                                    short* __restrict__ w2T) {
    __shared__ float tile[32][33];
    const int t = blockIdx.x;
    const float* src;
    short* dst;
    int K, N, kt, nt;
    if (t < 1024) {
        const int mat = t >> 8, tt = t & 255;
        kt = tt >> 4; nt = tt & 15; K = 512; N = 512;
        const float* s4 = (mat == 0) ? wq : (mat == 1) ? wk : (mat == 2) ? wv : wo;
        src = s4 + (long)l * 512 * 512;
        dst = (mat < 3) ? qkvT + mat * 512 * 512 : woT;
    } else if (t < 2048) {
        const int tt = t - 1024;
        kt = tt & 15; nt = tt >> 4; K = 512; N = 2048;
        src = w1 + (long)l * 512 * 2048; dst = w1T;
    } else {
        const int tt = t - 2048;
        kt = tt >> 4; nt = tt & 15; K = 2048; N = 512;
        src = w2 + (long)l * 2048 * 512; dst = w2T;
    }
    const int tx = threadIdx.x, ty = threadIdx.y;
#pragma unroll
    for (int i = 0; i < 4; ++i)
        tile[ty + i * 8][tx] = src[(long)(kt * 32 + ty + i * 8) * N + nt * 32 + tx];
    __syncthreads();
#pragma unroll
    for (int i = 0; i < 4; ++i)
        dst[(long)(nt * 32 + ty + i * 8) * K + kt * 32 + tx] = (short)f2bf(tile[tx][ty + i * 8]);
}

// ---------------- bf16 MFMA GEMM: C[M,N] = A[M,K] @ BT[N,K]^T --------------
// BM=128, BK=64, templated BN (128 or 64). 4 waves (2x2).
template <int BN, int BIAS, int RELU, int OUTBF>
__global__ __launch_bounds__(256) void mm_kernel(const short* __restrict__ A,
                                                 const short* __restrict__ BT,
                                                 const float* __restrict__ bias,
                                                 void* __restrict__ Cv,
                                                 int N, int K) {
    constexpr int NW = BN / 32;            // n-frags per wave
    __shared__ short As[128 * 64];
    __shared__ short Bs[BN * 64];
    const int tid = threadIdx.x;
    const int lane = tid & 63, wid = tid >> 6;
    const int wr = wid >> 1, wc = wid & 1;
    const int l15 = lane & 15, lhi = lane >> 4;
    const int row0 = blockIdx.y * 128, col0 = blockIdx.x * BN;

    f32x4 acc[4][NW];
#pragma unroll
    for (int m = 0; m < 4; ++m)
#pragma unroll
        for (int n = 0; n < NW; ++n) acc[m][n] = zf4();

    const int nt = K >> 6;
    for (int t = 0; t < nt; ++t) {
        const int k0 = t << 6;
        {
#pragma unroll
            for (int c = 0; c < 4; ++c) {
                const int p = c * 4096 + tid * 16;
                const int row = p >> 7, cb = p & 127;
                const char* ga = (const char*)A + ((long)(row0 + row) * K + k0) * 2 + cb;
                char* la = (char*)As + c * 4096 + wid * 1024;
                __builtin_amdgcn_global_load_lds((gl_void*)ga, (lds_void*)la, 16, 0, 0);
                if (c < BN / 32) {
                    const char* gb = (const char*)BT + ((long)(col0 + row) * K + k0) * 2 + cb;
                    char* lb = (char*)Bs + c * 4096 + wid * 1024;
                    __builtin_amdgcn_global_load_lds((gl_void*)gb, (lds_void*)lb, 16, 0, 0);
                }
            }
        }
        __syncthreads();
#pragma unroll
        for (int kk = 0; kk < 2; ++kk) {
            bf16x8 af[4], bf[NW];
#pragma unroll
            for (int m = 0; m < 4; ++m)
                af[m] = *(const bf16x8*)(As + (wr * 64 + m * 16 + l15) * 64 + kk * 32 + lhi * 8);
#pragma unroll
            for (int n = 0; n < NW; ++n)
                bf[n] = *(const bf16x8*)(Bs + (wc * (BN / 2) + n * 16 + l15) * 64 + kk * 32 + lhi * 8);
#pragma unroll
            for (int m = 0; m < 4; ++m)
#pragma unroll
                for (int n = 0; n < NW; ++n)
                    acc[m][n] = __builtin_amdgcn_mfma_f32_16x16x32_bf16(af[m], bf[n], acc[m][n], 0, 0, 0);
        }
        __syncthreads();
    }

    float* Cf = (float*)Cv;
    short* Cb = (short*)Cv;
#pragma unroll
    for (int m = 0; m < 4; ++m) {
        const int r0 = row0 + wr * 64 + m * 16 + lhi * 4;
#pragma unroll
        for (int n = 0; n < NW; ++n) {
            const int cc = col0 + wc * (BN / 2) + n * 16 + l15;
            const float bv = BIAS ? bias[cc] : 0.f;
#pragma unroll
            for (int j = 0; j < 4; ++j) {
                float v = acc[m][n][j] + bv;
                if (RELU) v = fmaxf(v, 0.f);
                const long idx = (long)(r0 + j) * N + cc;
                if (OUTBF) Cb[idx] = (short)f2bf(v);
                else Cf[idx] = v;
            }
        }
    }
}

// ---------------- V transpose: qkv v-cols -> vT [B,H,64,S] bf16 -------------
__global__ __launch_bounds__(256) void vtr_kernel(const short* __restrict__ qkv,
                                                  short* __restrict__ vT) {
    __shared__ short tile[32][33];
    const int dt = blockIdx.x;
    const int st = blockIdx.y;
    const int bh = blockIdx.z;
    const int b = bh >> 3, h = bh & 7;
    const int tx = threadIdx.x, ty = threadIdx.y;
    const short* src = qkv + ((long)b * TS + st * 32) * 1536 + 1024 + h * 64 + dt * 32;
#pragma unroll
    for (int i = 0; i < 4; ++i)
        tile[ty + i * 8][tx] = src[(long)(ty + i * 8) * 1536 + tx];
    __syncthreads();
    short* dst = vT + ((long)(bh * 64 + dt * 32)) * TS + st * 32;
#pragma unroll
    for (int i = 0; i < 4; ++i)
        dst[(long)(ty + i * 8) * TS + tx] = tile[tx][ty + i * 8];
}

// ---------------- bf16 MFMA flash attention (swapped QK^T, LDS-staged K/V) --
// 1D grid 512 blocks, XCD-swizzled. 4 waves/block; wave owns 16 q-rows.
__global__ __launch_bounds__(256) void attn_kernel(const short* __restrict__ qkv,
                                                   const short* __restrict__ vT,
                                                   short* __restrict__ ao) {
    __shared__ short Ks[2][4096];   // [buf] 64 rows x 128B, XOR-swizzled
    __shared__ short Vs[2][4096];   // [buf] V^T: 64 d-rows x 128B (64 k), swizzled
    __shared__ short Ps[4][1024];   // per-wave P [16 q][64 k], swizzled

    const int orig = blockIdx.x;
    const int wgid = (orig & 7) * 64 + (orig >> 3);   // XCD gets contiguous chunk
    const int qt = wgid & 31;
    const int bh = wgid >> 5;
    const int b = bh >> 3, h = bh & 7;
    const int tid = threadIdx.x, lane = tid & 63, wid = tid >> 6;
    const int l15 = lane & 15, lhi = lane >> 4;

    const long rq = (long)b * TS + qt * 64 + wid * 16 + l15;
    const bf16x8 qa0 = *(const bf16x8*)(qkv + rq * 1536 + h * 64 + lhi * 8);
    const bf16x8 qa1 = *(const bf16x8*)(qkv + rq * 1536 + h * 64 + 32 + lhi * 8);

    const char* kbase = (const char*)(qkv + ((long)b * TS) * 1536 + 512 + h * 64);
    const char* vbase = (const char*)(vT + ((long)(bh * 64)) * TS);

    const int rr = wid * 8 + (lane >> 3);                 // staging row within 32-band
    const int cswz = 16 * ((lane & 7) ^ (lane >> 3));     // pre-swizzled source col

    f32x4 o[4];
#pragma unroll
    for (int n = 0; n < 4; ++n) o[n] = zf4();
    float m_run = -1e30f, l_run = 0.f;

    // prologue stage kt=0 into buf 0
#pragma unroll
    for (int i = 0; i < 2; ++i) {
        const char* gk = kbase + (long)(i * 32 + rr) * 3072 + cswz;
        const char* gv = vbase + (long)(i * 32 + rr) * (TS * 2) + cswz;
        char* lk = (char*)&Ks[0][0] + i * 4096 + wid * 1024;
        char* lv = (char*)&Vs[0][0] + i * 4096 + wid * 1024;
        __builtin_amdgcn_global_load_lds((gl_void*)gk, (lds_void*)lk, 16, 0, 0);
        __builtin_amdgcn_global_load_lds((gl_void*)gv, (lds_void*)lv, 16, 0, 0);
    }
    __syncthreads();

    const int sw = (l15 & 7) << 4;
    char* pl = (char*)&Ps[wid][0];
    int cur = 0;

    for (int kt = 0; kt < TS / 64; ++kt) {
        // prefetch next tile into other buffer
        if (kt + 1 < TS / 64) {
#pragma unroll
            for (int i = 0; i < 2; ++i) {
                const char* gk = kbase + (long)((kt + 1) * 64 + i * 32 + rr) * 3072 + cswz;
                const char* gv = vbase + (long)(i * 32 + rr) * (TS * 2) + (kt + 1) * 128 + cswz;
                char* lk = (char*)&Ks[cur ^ 1][0] + i * 4096 + wid * 1024;
                char* lv = (char*)&Vs[cur ^ 1][0] + i * 4096 + wid * 1024;
                __builtin_amdgcn_global_load_lds((gl_void*)gk, (lds_void*)lk, 16, 0, 0);
                __builtin_amdgcn_global_load_lds((gl_void*)gv, (lds_void*)lv, 16, 0, 0);
            }
        }

        // ---- S^T = K @ Q^T : lane owns q-row l15, k = cf*16 + lhi*4 + j ----
        const char* kl = (const char*)&Ks[cur][0];
        f32x4 s[4];
        __builtin_amdgcn_s_setprio(1);
#pragma unroll
        for (int cf = 0; cf < 4; ++cf) {
            const int row = cf * 16 + l15;
            const bf16x8 k0 = *(const bf16x8*)(kl + row * 128 + ((lhi * 16) ^ sw));
            const bf16x8 k1 = *(const bf16x8*)(kl + row * 128 + ((64 + lhi * 16) ^ sw));
            f32x4 z = zf4();
            z = __builtin_amdgcn_mfma_f32_16x16x32_bf16(k0, qa0, z, 0, 0, 0);
            s[cf] = __builtin_amdgcn_mfma_f32_16x16x32_bf16(k1, qa1, z, 0, 0, 0);
        }
        __builtin_amdgcn_s_setprio(0);

        // ---- online softmax with defer-max (THR=8) ----
        float pv[16];
        float rm = -1e30f;
#pragma unroll
        for (int cf = 0; cf < 4; ++cf)
#pragma unroll
            for (int j = 0; j < 4; ++j) {
                const float v = s[cf][j] * 0.125f;
                pv[cf * 4 + j] = v;
                rm = fmaxf(rm, v);
            }
        rm = fmaxf(rm, __shfl_xor(rm, 16, 64));
        rm = fmaxf(rm, __shfl_xor(rm, 32, 64));
        const bool resc = !__all(rm <= m_run + 8.f);
        float scl = 1.f;
        if (resc) {
            const float mnew = fmaxf(m_run, rm);
            scl = __expf(m_run - mnew);
            m_run = mnew;
        }
        float rs = 0.f;
#pragma unroll
        for (int i = 0; i < 16; ++i) { pv[i] = __expf(pv[i] - m_run); rs += pv[i]; }
        rs += __shfl_xor(rs, 16, 64);
        rs += __shfl_xor(rs, 32, 64);
        if (resc) {
            l_run = l_run * scl + rs;
            const float s0 = __shfl(scl, lhi * 4 + 0, 64);
            const float s1 = __shfl(scl, lhi * 4 + 1, 64);
            const float s2 = __shfl(scl, lhi * 4 + 2, 64);
            const float s3 = __shfl(scl, lhi * 4 + 3, 64);
#pragma unroll
            for (int n = 0; n < 4; ++n) {
                o[n][0] *= s0; o[n][1] *= s1; o[n][2] *= s2; o[n][3] *= s3;
            }
        } else {
            l_run += rs;
        }

        // ---- write P (bf16 via v_cvt_pk) to per-wave LDS, row q = l15 ----
#pragma unroll
        for (int cf = 0; cf < 4; ++cf) {
            unsigned r0, r1;
            asm("v_cvt_pk_bf16_f32 %0, %1, %2" : "=v"(r0) : "v"(pv[cf * 4 + 0]), "v"(pv[cf * 4 + 1]));
            asm("v_cvt_pk_bf16_f32 %0, %1, %2" : "=v"(r1) : "v"(pv[cf * 4 + 2]), "v"(pv[cf * 4 + 3]));
            uint2 pk; pk.x = r0; pk.y = r1;
            *(uint2*)(pl + l15 * 128 + ((cf * 32 + lhi * 8) ^ sw)) = pk;
        }
        asm volatile("s_waitcnt lgkmcnt(0)" ::: "memory");
        __builtin_amdgcn_sched_barrier(0);

        // ---- O += P @ V (wave-local P, staged V^T) ----
        const bf16x8 pa0 = *(const bf16x8*)(pl + l15 * 128 + ((lhi * 16) ^ sw));
        const bf16x8 pa1 = *(const bf16x8*)(pl + l15 * 128 + ((64 + lhi * 16) ^ sw));
        const char* vl = (const char*)&Vs[cur][0];
        __builtin_amdgcn_s_setprio(1);
#pragma unroll
        for (int n = 0; n < 4; ++n) {
            const int row = n * 16 + l15;
            const bf16x8 v0 = *(const bf16x8*)(vl + row * 128 + ((lhi * 16) ^ sw));
            const bf16x8 v1 = *(const bf16x8*)(vl + row * 128 + ((64 + lhi * 16) ^ sw));
            o[n] = __builtin_amdgcn_mfma_f32_16x16x32_bf16(pa0, v0, o[n], 0, 0, 0);
            o[n] = __builtin_amdgcn_mfma_f32_16x16x32_bf16(pa1, v1, o[n], 0, 0, 0);
        }
        __builtin_amdgcn_s_setprio(0);
        __syncthreads();   // all waves done with K/V[cur] + staging loads landed
        cur ^= 1;
    }

    float invl[4];
#pragma unroll
    for (int j = 0; j < 4; ++j) invl[j] = 1.f / __shfl(l_run, lhi * 4 + j, 64);
    const long orow0 = (long)b * TS + qt * 64 + wid * 16 + lhi * 4;
#pragma unroll
    for (int n = 0; n < 4; ++n) {
        const int cc = h * 64 + n * 16 + l15;
#pragma unroll
        for (int j = 0; j < 4; ++j) {
            const float v = o[n][j] * invl[j];
            ao[(orow0 + j) * TD + cc] = (short)f2bf(v);
        }
    }
}

// ---------------- fused residual-add + LayerNorm (4 rows per block) ---------
__global__ __launch_bounds__(256) void addln_kernel(const float* __restrict__ a,
                                                    const float* __restrict__ res,
                                                    const float* __restrict__ g,
                                                    const float* __restrict__ bt,
                                                    float* __restrict__ out,
                                                    short* __restrict__ outb) {
    const int row = blockIdx.x * 4 + threadIdx.y;
    const int d0 = threadIdx.x * 8;
    const float* pa = a + (long)row * TD + d0;
    const float* pr = res + (long)row * TD + d0;
    float v[8];
    const float4 a0 = *(const float4*)pa, a1 = *(const float4*)(pa + 4);
    const float4 r0 = *(const float4*)pr, r1 = *(const float4*)(pr + 4);
    v[0] = a0.x + r0.x; v[1] = a0.y + r0.y; v[2] = a0.z + r0.z; v[3] = a0.w + r0.w;
    v[4] = a1.x + r1.x; v[5] = a1.y + r1.y; v[6] = a1.z + r1.z; v[7] = a1.w + r1.w;
    float s = 0.f, s2 = 0.f;
#pragma unroll
    for (int j = 0; j < 8; ++j) { s += v[j]; s2 += v[j] * v[j]; }
#pragma unroll
    for (int m = 1; m < 64; m <<= 1) {
        s += __shfl_xor(s, m, 64);
        s2 += __shfl_xor(s2, m, 64);
    }
    const float mean = s * (1.f / TD);
    const float var = s2 * (1.f / TD) - mean * mean;
    const float rstd = rsqrtf(var + TEPS);
    const float* pg = g + d0;
    const float* pb = bt + d0;
    float ov[8];
#pragma unroll
    for (int j = 0; j < 8; ++j) ov[j] = (v[j] - mean) * rstd * pg[j] + pb[j];
    float* po = out + (long)row * TD + d0;
    float4 o0, o1;
    o0.x = ov[0]; o0.y = ov[1]; o0.z = ov[2]; o0.w = ov[3];
    o1.x = ov[4]; o1.y = ov[5]; o1.z = ov[6]; o1.w = ov[7];
    *(float4*)po = o0;
    *(float4*)(po + 4) = o1;
    if (outb) {
        bf16x8 t;
#pragma unroll
        for (int j = 0; j < 8; ++j) t[j] = (short)f2bf(ov[j]);
        *(bf16x8*)(outb + (long)row * TD + d0) = t;
    }
}

extern "C" void kernel_launch(void* const* d_in, const int* in_sizes, int n_in,
                              void* d_out, int out_size, void* d_ws, size_t ws_size,
                              hipStream_t stream) {
    const int* tokens = (const int*)d_in[0];
    const float* emb = (const float*)d_in[1];
    const float* wq = (const float*)d_in[2];
    const float* wk = (const float*)d_in[3];
    const float* wv = (const float*)d_in[4];
    const float* wo = (const float*)d_in[5];
    const float* w1 = (const float*)d_in[6];
    const float* b1 = (const float*)d_in[7];
    const float* w2 = (const float*)d_in[8];
    const float* b2 = (const float*)d_in[9];
    const float* g1 = (const float*)d_in[10];
    const float* be1 = (const float*)d_in[11];
    const float* g2 = (const float*)d_in[12];
    const float* be2 = (const float*)d_in[13];

    float* ws = (float*)d_ws;
    float* x = ws;                         // f32 residual stream [M,512]
    float* tmp = ws + ND;                  // f32 gemm output [M,512]
    short* sb = (short*)(ws + 2 * ND);
    short* xb = sb;                        // bf16 x copy
    short* share = sb + ND;
    short* qkv = share;                    // [M,1536]
    short* vTb = share + (long)4096 * 1536;// [B,H,64,S]
    short* ff = share;                     // [M,2048] (FF phase)
    short* aob = share + 8388608;          // attn out bf16
    short* wT = aob + ND;
    short* qkvT = wT;
    short* woT = qkvT + 1536 * 512;
    short* w1T = woT + 512 * 512;
    short* w2T = w1T + 2048 * 512;
    float* out = (float*)d_out;

    embed_kernel<<<NBS, 64, 0, stream>>>(tokens, emb, x, xb);

    const dim3 blk256(256);
    const dim3 blkT(32, 8);
    const dim3 blkLN(64, 4);
    const dim3 gQKV(1536 / 128, NBS / 128);   // (12, 32)
    const dim3 gD64(512 / 64, NBS / 128);     // (8, 32)
    const dim3 gF(2048 / 128, NBS / 128);     // (16, 32)
    const dim3 gV(2, TS / 32, TB * TH);

    for (int l = 0; l < TL; ++l) {
        wprep_kernel<<<3072, blkT, 0, stream>>>(wq, wk, wv, wo, w1, w2, l, qkvT, woT, w1T, w2T);
        mm_kernel<128, 0, 0, 1><<<gQKV, blk256, 0, stream>>>(xb, qkvT, nullptr, qkv, 1536, 512);
        vtr_kernel<<<gV, blkT, 0, stream>>>(qkv, vTb);
        attn_kernel<<<512, blk256, 0, stream>>>(qkv, vTb, aob);
        mm_kernel<64, 0, 0, 0><<<gD64, blk256, 0, stream>>>(aob, woT, nullptr, tmp, 512, 512);
        addln_kernel<<<NBS / 4, blkLN, 0, stream>>>(tmp, x, g1 + (long)l * TD, be1 + (long)l * TD, x, xb);
        mm_kernel<128, 1, 1, 1><<<gF, blk256, 0, stream>>>(xb, w1T, b1 + (long)l * TF, ff, 2048, 512);
        mm_kernel<64, 1, 0, 0><<<gD64, blk256, 0, stream>>>(ff, w2T, b2 + (long)l * TD, tmp, 512, 2048);
        if (l == TL - 1) {
            addln_kernel<<<NBS / 4, blkLN, 0, stream>>>(tmp, x, g2 + (long)l * TD, be2 + (long)l * TD, out, nullptr);
        } else {
            addln_kernel<<<NBS / 4, blkLN, 0, stream>>>(tmp, x, g2 + (long)l * TD, be2 + (long)l * TD, x, xb);
        }
    }
}

// Round 6
// 677.212 us; speedup vs baseline: 4.8271x; 1.0824x over previous
//
#include <hip/hip_runtime.h>
#include <math.h>

#define TV 32000
#define TD 512
#define TS 2048
#define TH 8
#define TF 2048
#define TL 4
#define TB 2
#define THD 64
#define TEPS 1e-5f
#define NBS (TB * TS)               // 4096 token rows
#define ND ((long)NBS * TD)         // 2097152 elements per activation buffer

typedef short bf16x8 __attribute__((ext_vector_type(8)));
typedef short bf16x4 __attribute__((ext_vector_type(4)));
typedef float f32x4 __attribute__((ext_vector_type(4)));
typedef __attribute__((address_space(3))) void lds_void;
typedef const __attribute__((address_space(1))) void gl_void;

__device__ __forceinline__ unsigned short f2bf(float f) {
    unsigned u = __builtin_bit_cast(unsigned, f);
    unsigned r = (u + 0x7fffu + ((u >> 16) & 1u)) >> 16;
    return (unsigned short)r;
}

__device__ __forceinline__ f32x4 zf4() {
    f32x4 z = {0.f, 0.f, 0.f, 0.f};
    return z;
}

// v_exp_f32: D = 2^S0. s_nop guards the trans-op use-latency for the
// compiler-invisible inline-asm result.
__device__ __forceinline__ float fexp2(float x) {
    float r;
    asm("v_exp_f32 %0, %1\n\ts_nop 0" : "=v"(r) : "v"(x));
    return r;
}

// ---------------- embedding + sinusoidal positional encoding ----------------
__global__ __launch_bounds__(64) void embed_kernel(const int* __restrict__ tokens,
                                                   const float* __restrict__ emb,
                                                   float* __restrict__ x,
                                                   short* __restrict__ xb) {
    const int bs = blockIdx.x;
    const int s = bs & (TS - 1);
    const int tok = tokens[bs];
    const float* e = emb + (long)tok * TD;
    const int d0 = threadIdx.x * 8;
    float v[8];
#pragma unroll
    for (int j = 0; j < 8; ++j) {
        const int d = d0 + j;
        const float div = expf((float)(d & ~1) * (-9.210340371976184f / (float)TD));
        const float ang = (float)s * div;
        const float pe = (d & 1) ? cosf(ang) : sinf(ang);
        v[j] = e[d] + pe;
    }
    float* xo = x + (long)bs * TD + d0;
    float4 o0, o1;
    o0.x = v[0]; o0.y = v[1]; o0.z = v[2]; o0.w = v[3];
    o1.x = v[4]; o1.y = v[5]; o1.z = v[6]; o1.w = v[7];
    *(float4*)xo = o0;
    *(float4*)(xo + 4) = o1;
    bf16x8 t;
#pragma unroll
    for (int j = 0; j < 8; ++j) t[j] = (short)f2bf(v[j]);
    *(bf16x8*)(xb + (long)bs * TD + d0) = t;
}

// ---------------- weight prep: fp32 [K,N] -> bf16 [N,K], all 6 mats/layer ---
__global__ __launch_bounds__(256) void wprep_kernel(const float* __restrict__ wq,
                                                    const float* __restrict__ wk,
                                                    const float* __restrict__ wv,
                                                    const float* __restrict__ wo,
                                                    const float* __restrict__ w1,
                                                    const float* __restrict__ w2,
                                                    int l,
                                                    short* __restrict__ qkvT,
                                                    short* __restrict__ woT,
                                                    short* __restrict__ w1T,
                                                    short* __restrict__ w2T) {
    __shared__ float tile[32][33];
    const int t = blockIdx.x;
    const float* src;
    short* dst;
    int K, N, kt, nt;
    if (t < 1024) {
        const int mat = t >> 8, tt = t & 255;
        kt = tt >> 4; nt = tt & 15; K = 512; N = 512;
        const float* s4 = (mat == 0) ? wq : (mat == 1) ? wk : (mat == 2) ? wv : wo;
        src = s4 + (long)l * 512 * 512;
        dst = (mat < 3) ? qkvT + mat * 512 * 512 : woT;
    } else if (t < 2048) {
        const int tt = t - 1024;
        kt = tt & 15; nt = tt >> 4; K = 512; N = 2048;
        src = w1 + (long)l * 512 * 2048; dst = w1T;
    } else {
        const int tt = t - 2048;
        kt = tt >> 4; nt = tt & 15; K = 2048; N = 512;
        src = w2 + (long)l * 2048 * 512; dst = w2T;
    }
    const int tx = threadIdx.x, ty = threadIdx.y;
#pragma unroll
    for (int i = 0; i < 4; ++i)
        tile[ty + i * 8][tx] = src[(long)(kt * 32 + ty + i * 8) * N + nt * 32 + tx];
    __syncthreads();
#pragma unroll
    for (int i = 0; i < 4; ++i)
        dst[(long)(nt * 32 + ty + i * 8) * K + kt * 32 + tx] = (short)f2bf(tile[tx][ty + i * 8]);
}

// ---------------- bf16 MFMA GEMM: C[M,N] = A[M,K] @ BT[N,K]^T --------------
// Templated BM x BN tile, BK=64, 4 waves (2x2), double-buffered 2-phase loop:
// STAGE(next) issued before compute(cur); ONE barrier per K-step.
template <int BM, int BN, int BIAS, int RELU, int OUTBF>
__global__ __launch_bounds__(256) void mm_kernel(const short* __restrict__ A,
                                                 const short* __restrict__ BT,
                                                 const float* __restrict__ bias,
                                                 void* __restrict__ Cv,
                                                 int N, int K) {
    constexpr int MW = BM / 32;            // m-frags per wave
    constexpr int NW = BN / 32;            // n-frags per wave
    __shared__ short As[2][BM * 64];
    __shared__ short Bs[2][BN * 64];
    const int tid = threadIdx.x;
    const int lane = tid & 63, wid = tid >> 6;
    const int wr = wid >> 1, wc = wid & 1;
    const int l15 = lane & 15, lhi = lane >> 4;
    const int row0 = blockIdx.y * BM, col0 = blockIdx.x * BN;

    auto stage = [&](int buf, int k0) {
#pragma unroll
        for (int c = 0; c < BM / 32; ++c) {
            const int p = c * 4096 + tid * 16;
            const int row = p >> 7, cb = p & 127;
            const char* ga = (const char*)A + ((long)(row0 + row) * K + k0) * 2 + cb;
            __builtin_amdgcn_global_load_lds((gl_void*)ga,
                (lds_void*)((char*)As[buf] + c * 4096 + wid * 1024), 16, 0, 0);
        }
#pragma unroll
        for (int c = 0; c < BN / 32; ++c) {
            const int p = c * 4096 + tid * 16;
            const int row = p >> 7, cb = p & 127;
            const char* gb = (const char*)BT + ((long)(col0 + row) * K + k0) * 2 + cb;
            __builtin_amdgcn_global_load_lds((gl_void*)gb,
                (lds_void*)((char*)Bs[buf] + c * 4096 + wid * 1024), 16, 0, 0);
        }
    };

    f32x4 acc[MW][NW];
#pragma unroll
    for (int m = 0; m < MW; ++m)
#pragma unroll
        for (int n = 0; n < NW; ++n) acc[m][n] = zf4();

    const int nt = K >> 6;
    stage(0, 0);
    __syncthreads();
    int cur = 0;
    for (int t = 0; t < nt; ++t) {
        if (t + 1 < nt) stage(cur ^ 1, (t + 1) << 6);
#pragma unroll
        for (int kk = 0; kk < 2; ++kk) {
            bf16x8 af[MW], bfr[NW];
#pragma unroll
            for (int m = 0; m < MW; ++m)
                af[m] = *(const bf16x8*)(As[cur] + (wr * (BM / 2) + m * 16 + l15) * 64 + kk * 32 + lhi * 8);
#pragma unroll
            for (int n = 0; n < NW; ++n)
                bfr[n] = *(const bf16x8*)(Bs[cur] + (wc * (BN / 2) + n * 16 + l15) * 64 + kk * 32 + lhi * 8);
#pragma unroll
            for (int m = 0; m < MW; ++m)
#pragma unroll
                for (int n = 0; n < NW; ++n)
                    acc[m][n] = __builtin_amdgcn_mfma_f32_16x16x32_bf16(af[m], bfr[n], acc[m][n], 0, 0, 0);
        }
        __syncthreads();   // drains prefetch (vmcnt) + all waves done reading cur
        cur ^= 1;
    }

    float* Cf = (float*)Cv;
    short* Cb = (short*)Cv;
#pragma unroll
    for (int m = 0; m < MW; ++m) {
        const int r0 = row0 + wr * (BM / 2) + m * 16 + lhi * 4;
#pragma unroll
        for (int n = 0; n < NW; ++n) {
            const int cc = col0 + wc * (BN / 2) + n * 16 + l15;
            const float bv = BIAS ? bias[cc] : 0.f;
#pragma unroll
            for (int j = 0; j < 4; ++j) {
                float v = acc[m][n][j] + bv;
                if (RELU) v = fmaxf(v, 0.f);
                const long idx = (long)(r0 + j) * N + cc;
                if (OUTBF) Cb[idx] = (short)f2bf(v);
                else Cf[idx] = v;
            }
        }
    }
}

// ---------------- V transpose: qkv v-cols -> vT [B,H,64,S] bf16 -------------
__global__ __launch_bounds__(256) void vtr_kernel(const short* __restrict__ qkv,
                                                  short* __restrict__ vT) {
    __shared__ short tile[32][33];
    const int dt = blockIdx.x;
    const int st = blockIdx.y;
    const int bh = blockIdx.z;
    const int b = bh >> 3, h = bh & 7;
    const int tx = threadIdx.x, ty = threadIdx.y;
    const short* src = qkv + ((long)b * TS + st * 32) * 1536 + 1024 + h * 64 + dt * 32;
#pragma unroll
    for (int i = 0; i < 4; ++i)
        tile[ty + i * 8][tx] = src[(long)(ty + i * 8) * 1536 + tx];
    __syncthreads();
    short* dst = vT + ((long)(bh * 64 + dt * 32)) * TS + st * 32;
#pragma unroll
    for (int i = 0; i < 4; ++i)
        dst[(long)(ty + i * 8) * TS + tx] = tile[tx][ty + i * 8];
}

// ---------------- bf16 MFMA flash attention, KVBLK=128 ----------------------
// 1D grid 512 blocks, XCD-swizzled. 4 waves; wave owns 16 q-rows.
// Swapped QK^T (lane-local softmax), exp2-domain, defer-max, dbuf K/V staging.
#define SCL2 0.18033688011112042f   /* 0.125 * log2(e) */
#define THR2 11.541560327111708f    /* 8 * log2(e) */
__global__ __launch_bounds__(256) void attn_kernel(const short* __restrict__ qkv,
                                                   const short* __restrict__ vT,
                                                   short* __restrict__ ao) {
    __shared__ short Ks[2][128 * 64];   // 128 k-rows x 64 d (128B rows, 8-gran swz)
    __shared__ short Vs[2][64 * 128];   // 64 d-rows x 128 k (256B rows, 16-gran swz)
    __shared__ short Ps[4][16 * 128];   // per-wave P: 16 q x 128 k (256B rows, swz)

    const int orig = blockIdx.x;
    const int wgid = (orig & 7) * 64 + (orig >> 3);   // XCD gets contiguous chunk
    const int qt = wgid & 31;
    const int bh = wgid >> 5;
    const int b = bh >> 3, h = bh & 7;
    const int tid = threadIdx.x, lane = tid & 63, wid = tid >> 6;
    const int l15 = lane & 15, lhi = lane >> 4;

    const long rq = (long)b * TS + qt * 64 + wid * 16 + l15;
    const bf16x8 qa0 = *(const bf16x8*)(qkv + rq * 1536 + h * 64 + lhi * 8);
    const bf16x8 qa1 = *(const bf16x8*)(qkv + rq * 1536 + h * 64 + 32 + lhi * 8);

    const char* kbase = (const char*)(qkv + ((long)b * TS) * 1536 + 512 + h * 64);
    const char* vbase = (const char*)(vT + ((long)(bh * 64)) * TS);

    const int krow = tid >> 3;                        // 0..31 (128B K rows)
    const int kcsw = 16 * ((tid & 7) ^ (krow & 7));   // pre-swizzled K src col
    const int vrow = tid >> 4;                        // 0..15 (256B V rows)
    const int vcsw = 16 * ((tid & 15) ^ vrow);        // pre-swizzled V src col

    auto stage = [&](int buf, int kt) {
#pragma unroll
        for (int i = 0; i < 4; ++i) {
            const char* gk = kbase + (long)(kt * 128 + i * 32 + krow) * 3072 + kcsw;
            const char* gv = vbase + (long)(i * 16 + vrow) * (TS * 2) + kt * 256 + vcsw;
            __builtin_amdgcn_global_load_lds((gl_void*)gk,
                (lds_void*)((char*)Ks[buf] + i * 4096 + wid * 1024), 16, 0, 0);
            __builtin_amdgcn_global_load_lds((gl_void*)gv,
                (lds_void*)((char*)Vs[buf] + i * 4096 + wid * 1024), 16, 0, 0);
        }
    };

    f32x4 o[4];
#pragma unroll
    for (int n = 0; n < 4; ++n) o[n] = zf4();
    float m_run = -1e30f, l_run = 0.f;

    stage(0, 0);
    __syncthreads();

    const int sw = (l15 & 7) << 4;
    const int sw16 = l15 << 4;
    char* pl = (char*)&Ps[wid][0];
    int cur = 0;

    for (int kt = 0; kt < TS / 128; ++kt) {
        if (kt + 1 < TS / 128) stage(cur ^ 1, kt + 1);

        // ---- S^T = K @ Q^T : lane owns q-row l15, k = cf*16 + lhi*4 + j ----
        const char* kl = (const char*)Ks[cur];
        f32x4 s[8];
        __builtin_amdgcn_s_setprio(1);
#pragma unroll
        for (int cf = 0; cf < 8; ++cf) {
            const int row = cf * 16 + l15;
            const bf16x8 k0 = *(const bf16x8*)(kl + row * 128 + ((lhi * 16) ^ sw));
            const bf16x8 k1 = *(const bf16x8*)(kl + row * 128 + ((64 + lhi * 16) ^ sw));
            f32x4 z = zf4();
            z = __builtin_amdgcn_mfma_f32_16x16x32_bf16(k0, qa0, z, 0, 0, 0);
            s[cf] = __builtin_amdgcn_mfma_f32_16x16x32_bf16(k1, qa1, z, 0, 0, 0);
        }
        __builtin_amdgcn_s_setprio(0);

        // ---- online softmax (log2 domain) with defer-max ----
        float pv[32];
        float rm = -1e30f;
#pragma unroll
        for (int cf = 0; cf < 8; ++cf)
#pragma unroll
            for (int j = 0; j < 4; ++j) {
                const float v = s[cf][j] * SCL2;
                pv[cf * 4 + j] = v;
                rm = fmaxf(rm, v);
            }
        rm = fmaxf(rm, __shfl_xor(rm, 16, 64));
        rm = fmaxf(rm, __shfl_xor(rm, 32, 64));
        const bool resc = !__all(rm <= m_run + THR2);
        float scl = 1.f;
        if (resc) {
            const float mnew = fmaxf(m_run, rm);
            scl = fexp2(m_run - mnew);
            m_run = mnew;
        }
        float rs = 0.f;
#pragma unroll
        for (int i = 0; i < 32; ++i) { pv[i] = fexp2(pv[i] - m_run); rs += pv[i]; }
        rs += __shfl_xor(rs, 16, 64);
        rs += __shfl_xor(rs, 32, 64);
        if (resc) {
            l_run = l_run * scl + rs;
            const float s0 = __shfl(scl, lhi * 4 + 0, 64);
            const float s1 = __shfl(scl, lhi * 4 + 1, 64);
            const float s2 = __shfl(scl, lhi * 4 + 2, 64);
            const float s3 = __shfl(scl, lhi * 4 + 3, 64);
#pragma unroll
            for (int n = 0; n < 4; ++n) {
                o[n][0] *= s0; o[n][1] *= s1; o[n][2] *= s2; o[n][3] *= s3;
            }
        } else {
            l_run += rs;
        }

        // ---- write P (bf16 via v_cvt_pk) to per-wave LDS, row q = l15 ----
#pragma unroll
        for (int cf = 0; cf < 8; ++cf) {
            unsigned r0, r1;
            asm("v_cvt_pk_bf16_f32 %0, %1, %2" : "=v"(r0) : "v"(pv[cf * 4 + 0]), "v"(pv[cf * 4 + 1]));
            asm("v_cvt_pk_bf16_f32 %0, %1, %2" : "=v"(r1) : "v"(pv[cf * 4 + 2]), "v"(pv[cf * 4 + 3]));
            uint2 pk; pk.x = r0; pk.y = r1;
            *(uint2*)(pl + l15 * 256 + ((cf * 32 + lhi * 8) ^ sw16)) = pk;
        }
        asm volatile("s_waitcnt lgkmcnt(0)" ::: "memory");
        __builtin_amdgcn_sched_barrier(0);

        // ---- O += P @ V (wave-local P, staged V^T) ----
        bf16x8 pa[4];
#pragma unroll
        for (int kk = 0; kk < 4; ++kk)
            pa[kk] = *(const bf16x8*)(pl + l15 * 256 + ((kk * 64 + lhi * 16) ^ sw16));
        const char* vl = (const char*)Vs[cur];
        __builtin_amdgcn_s_setprio(1);
#pragma unroll
        for (int n = 0; n < 4; ++n) {
            const int row = n * 16 + l15;
#pragma unroll
            for (int kk = 0; kk < 4; ++kk) {
                const bf16x8 vv = *(const bf16x8*)(vl + row * 256 + ((kk * 64 + lhi * 16) ^ sw16));
                o[n] = __builtin_amdgcn_mfma_f32_16x16x32_bf16(pa[kk], vv, o[n], 0, 0, 0);
            }
        }
        __builtin_amdgcn_s_setprio(0);
        __syncthreads();   // prefetch landed + all waves done with K/V[cur]
        cur ^= 1;
    }

    float invl[4];
#pragma unroll
    for (int j = 0; j < 4; ++j) invl[j] = 1.f / __shfl(l_run, lhi * 4 + j, 64);
    const long orow0 = (long)b * TS + qt * 64 + wid * 16 + lhi * 4;
#pragma unroll
    for (int n = 0; n < 4; ++n) {
        const int cc = h * 64 + n * 16 + l15;
#pragma unroll
        for (int j = 0; j < 4; ++j) {
            const float v = o[n][j] * invl[j];
            ao[(orow0 + j) * TD + cc] = (short)f2bf(v);
        }
    }
}

// ---------------- fused residual-add + LayerNorm (4 rows per block) ---------
__global__ __launch_bounds__(256) void addln_kernel(const float* __restrict__ a,
                                                    const float* __restrict__ res,
                                                    const float* __restrict__ g,
                                                    const float* __restrict__ bt,
                                                    float* __restrict__ out,
                                                    short* __restrict__ outb) {
    const int row = blockIdx.x * 4 + threadIdx.y;
    const int d0 = threadIdx.x * 8;
    const float* pa = a + (long)row * TD + d0;
    const float* pr = res + (long)row * TD + d0;
    float v[8];
    const float4 a0 = *(const float4*)pa, a1 = *(const float4*)(pa + 4);
    const float4 r0 = *(const float4*)pr, r1 = *(const float4*)(pr + 4);
    v[0] = a0.x + r0.x; v[1] = a0.y + r0.y; v[2] = a0.z + r0.z; v[3] = a0.w + r0.w;
    v[4] = a1.x + r1.x; v[5] = a1.y + r1.y; v[6] = a1.z + r1.z; v[7] = a1.w + r1.w;
    float s = 0.f, s2 = 0.f;
#pragma unroll
    for (int j = 0; j < 8; ++j) { s += v[j]; s2 += v[j] * v[j]; }
#pragma unroll
    for (int m = 1; m < 64; m <<= 1) {
        s += __shfl_xor(s, m, 64);
        s2 += __shfl_xor(s2, m, 64);
    }
    const float mean = s * (1.f / TD);
    const float var = s2 * (1.f / TD) - mean * mean;
    const float rstd = rsqrtf(var + TEPS);
    const float* pg = g + d0;
    const float* pb = bt + d0;
    float ov[8];
#pragma unroll
    for (int j = 0; j < 8; ++j) ov[j] = (v[j] - mean) * rstd * pg[j] + pb[j];
    float* po = out + (long)row * TD + d0;
    float4 o0, o1;
    o0.x = ov[0]; o0.y = ov[1]; o0.z = ov[2]; o0.w = ov[3];
    o1.x = ov[4]; o1.y = ov[5]; o1.z = ov[6]; o1.w = ov[7];
    *(float4*)po = o0;
    *(float4*)(po + 4) = o1;
    if (outb) {
        bf16x8 t;
#pragma unroll
        for (int j = 0; j < 8; ++j) t[j] = (short)f2bf(ov[j]);
        *(bf16x8*)(outb + (long)row * TD + d0) = t;
    }
}

extern "C" void kernel_launch(void* const* d_in, const int* in_sizes, int n_in,
                              void* d_out, int out_size, void* d_ws, size_t ws_size,
                              hipStream_t stream) {
    const int* tokens = (const int*)d_in[0];
    const float* emb = (const float*)d_in[1];
    const float* wq = (const float*)d_in[2];
    const float* wk = (const float*)d_in[3];
    const float* wv = (const float*)d_in[4];
    const float* wo = (const float*)d_in[5];
    const float* w1 = (const float*)d_in[6];
    const float* b1 = (const float*)d_in[7];
    const float* w2 = (const float*)d_in[8];
    const float* b2 = (const float*)d_in[9];
    const float* g1 = (const float*)d_in[10];
    const float* be1 = (const float*)d_in[11];
    const float* g2 = (const float*)d_in[12];
    const float* be2 = (const float*)d_in[13];

    float* ws = (float*)d_ws;
    float* x = ws;                         // f32 residual stream [M,512]
    float* tmp = ws + ND;                  // f32 gemm output [M,512]
    short* sb = (short*)(ws + 2 * ND);
    short* xb = sb;                        // bf16 x copy
    short* share = sb + ND;
    short* qkv = share;                    // [M,1536]
    short* vTb = share + (long)4096 * 1536;// [B,H,64,S]
    short* ff = share;                     // [M,2048] (FF phase)
    short* aob = share + 8388608;          // attn out bf16
    short* wT = aob + ND;
    short* qkvT = wT;
    short* woT = qkvT + 1536 * 512;
    short* w1T = woT + 512 * 512;
    short* w2T = w1T + 2048 * 512;
    float* out = (float*)d_out;

    embed_kernel<<<NBS, 64, 0, stream>>>(tokens, emb, x, xb);

    const dim3 blk256(256);
    const dim3 blkT(32, 8);
    const dim3 blkLN(64, 4);
    const dim3 gQKV(1536 / 64, NBS / 128);   // (24, 32) BM=128,BN=64
    const dim3 gWO(512 / 64, NBS / 64);      // (8, 64)  BM=64, BN=64
    const dim3 gFF1(2048 / 64, NBS / 128);   // (32, 32) BM=128,BN=64
    const dim3 gFF2(512 / 64, NBS / 64);     // (8, 64)  BM=64, BN=64
    const dim3 gV(2, TS / 32, TB * TH);

    for (int l = 0; l < TL; ++l) {
        wprep_kernel<<<3072, blkT, 0, stream>>>(wq, wk, wv, wo, w1, w2, l, qkvT, woT, w1T, w2T);
        mm_kernel<128, 64, 0, 0, 1><<<gQKV, blk256, 0, stream>>>(xb, qkvT, nullptr, qkv, 1536, 512);
        vtr_kernel<<<gV, blkT, 0, stream>>>(qkv, vTb);
        attn_kernel<<<512, blk256, 0, stream>>>(qkv, vTb, aob);
        mm_kernel<64, 64, 0, 0, 0><<<gWO, blk256, 0, stream>>>(aob, woT, nullptr, tmp, 512, 512);
        addln_kernel<<<NBS / 4, blkLN, 0, stream>>>(tmp, x, g1 + (long)l * TD, be1 + (long)l * TD, x, xb);
        mm_kernel<128, 64, 1, 1, 1><<<gFF1, blk256, 0, stream>>>(xb, w1T, b1 + (long)l * TF, ff, 2048, 512);
        mm_kernel<64, 64, 1, 0, 0><<<gFF2, blk256, 0, stream>>>(ff, w2T, b2 + (long)l * TD, tmp, 512, 2048);
        if (l == TL - 1) {
            addln_kernel<<<NBS / 4, blkLN, 0, stream>>>(tmp, x, g2 + (long)l * TD, be2 + (long)l * TD, out, nullptr);
        } else {
            addln_kernel<<<NBS / 4, blkLN, 0, stream>>>(tmp, x, g2 + (long)l * TD, be2 + (long)l * TD, x, xb);
        }
    }
}